// Round 1
// baseline (2045.295 us; speedup 1.0000x reference)
//
#include <hip/hip_runtime.h>
#include <math.h>

// ---------- helpers ----------
__device__ __forceinline__ unsigned f2key(float f) {
    unsigned u = __float_as_uint(f);
    return (u & 0x80000000u) ? ~u : (u | 0x80000000u);
}
__device__ __forceinline__ float key2f(unsigned k) {
    return (k & 0x80000000u) ? __uint_as_float(k & 0x7fffffffu)
                             : __uint_as_float(~k);
}

#define KEY_NEG_INF 0x007FFFFFu  // f2key(-inf)

// ---------- 0: init ----------
__global__ void init_kernel(unsigned* m1k, unsigned* m2k, float* s1, float* s2,
                            float* msg1, float* msg2, int n1, int n2) {
    int i = blockIdx.x * blockDim.x + threadIdx.x;
    if (i < n1) { m1k[i] = KEY_NEG_INF; s1[i] = 0.f; }
    if (i < n2) { m2k[i] = KEY_NEG_INF; s2[i] = 0.f; }
    if (i < n1 * 64) msg1[i] = 0.f;
    if (i < n2 * 64) msg2[i] = 0.f;
}

// ---------- 1: K/V projection: K = X@Wk, V = X@Wv ----------
__global__ void proj_kernel(const float* __restrict__ X, int N,
                            const float* __restrict__ Wk,
                            const float* __restrict__ Wv,
                            float* __restrict__ K, float* __restrict__ V) {
    __shared__ float sWk[64 * 64];
    __shared__ float sWv[64 * 64];
    int tid = threadIdx.x;
    for (int i = tid; i < 4096; i += blockDim.x) { sWk[i] = Wk[i]; sWv[i] = Wv[i]; }
    __syncthreads();
    int wave = tid >> 6, lane = tid & 63;
    int wpb = blockDim.x >> 6;
    for (int n = blockIdx.x * wpb + wave; n < N; n += gridDim.x * wpb) {
        float x = X[n * 64 + lane];
        float ak = 0.f, av = 0.f;
#pragma unroll
        for (int k = 0; k < 64; ++k) {
            float xv = __shfl(x, k);
            ak = fmaf(xv, sWk[k * 64 + lane], ak);
            av = fmaf(xv, sWv[k * 64 + lane], av);
        }
        K[n * 64 + lane] = ak;
        V[n * 64 + lane] = av;
    }
}

// ---------- 2: edge logits + segment max ----------
__global__ void logit_kernel(const float* __restrict__ K1, const float* __restrict__ K2,
                             const int* __restrict__ seg1, const int* __restrict__ seg2,
                             float* __restrict__ trans,
                             unsigned* m1k, unsigned* m2k, int E) {
    int tid = blockIdx.x * blockDim.x + threadIdx.x;
    int e = tid >> 4, g = tid & 15;
    if (e >= E) return;
    int i1 = seg1[e], i2 = seg2[e];
    float4 a = ((const float4*)(K1 + (long)i1 * 64))[g];
    float4 b = ((const float4*)(K2 + (long)i2 * 64))[g];
    float d = a.x * b.x + a.y * b.y + a.z * b.z + a.w * b.w;
    d += __shfl_xor(d, 1);
    d += __shfl_xor(d, 2);
    d += __shfl_xor(d, 4);
    d += __shfl_xor(d, 8);
    if (g == 0) {
        trans[e] = d;
        unsigned k = f2key(d);
        atomicMax(&m1k[i1], k);
        atomicMax(&m2k[i2], k);
    }
}

// ---------- 3: exp + segment sum ----------
__global__ void exp_kernel(const float* __restrict__ trans,
                           const int* __restrict__ seg1, const int* __restrict__ seg2,
                           const unsigned* __restrict__ m1k, const unsigned* __restrict__ m2k,
                           float* s1, float* s2,
                           float* __restrict__ e1, float* __restrict__ e2,
                           int E, float invT) {
    int e = blockIdx.x * blockDim.x + threadIdx.x;
    if (e >= E) return;
    float t = trans[e];
    int i1 = seg1[e], i2 = seg2[e];
    float w1 = __expf((t - key2f(m1k[i1])) * invT);
    float w2 = __expf((t - key2f(m2k[i2])) * invT);
    e1[e] = w1;
    e2[e] = w2;
    atomicAdd(&s1[i1], w1);
    atomicAdd(&s2[i2], w2);
}

// ---------- 4: normalize + message scatter ----------
__global__ void scatter_kernel(const float* __restrict__ V1, const float* __restrict__ V2,
                               const int* __restrict__ seg1, const int* __restrict__ seg2,
                               const float* __restrict__ s1, const float* __restrict__ s2,
                               float* __restrict__ e1, float* __restrict__ e2,
                               float* msg1, float* msg2, int E) {
    int tid = blockIdx.x * blockDim.x + threadIdx.x;
    int e = tid >> 4, g = tid & 15;
    if (e >= E) return;
    int i1 = seg1[e], i2 = seg2[e];
    float w1 = e1[e] / (s1[i1] + 1e-8f);
    float w2 = e2[e] / (s2[i2] + 1e-8f);
    if (g == 0) { e1[e] = w1; e2[e] = w2; }
    float4 v2 = ((const float4*)(V2 + (long)i2 * 64))[g];
    float4 v1 = ((const float4*)(V1 + (long)i1 * 64))[g];
    float* p1 = msg1 + (long)i1 * 64 + g * 4;
    float* p2 = msg2 + (long)i2 * 64 + g * 4;
    atomicAdd(p1 + 0, w1 * v2.x);
    atomicAdd(p1 + 1, w1 * v2.y);
    atomicAdd(p1 + 2, w1 * v2.z);
    atomicAdd(p1 + 3, w1 * v2.w);
    atomicAdd(p2 + 0, w2 * v1.x);
    atomicAdd(p2 + 1, w2 * v1.y);
    atomicAdd(p2 + 2, w2 * v1.z);
    atomicAdd(p2 + 3, w2 * v1.w);
}

// ---------- 5: out GEMM + bias + leaky relu (in place) ----------
__global__ void out_kernel(float* __restrict__ msg, int N,
                           const float* __restrict__ Wo,
                           const float* __restrict__ bo) {
    __shared__ float sW[64 * 64];
    int tid = threadIdx.x;
    for (int i = tid; i < 4096; i += blockDim.x) sW[i] = Wo[i];
    __syncthreads();
    int wave = tid >> 6, lane = tid & 63;
    int wpb = blockDim.x >> 6;
    float b = bo[lane];
    for (int n = blockIdx.x * wpb + wave; n < N; n += gridDim.x * wpb) {
        float x = msg[n * 64 + lane];
        float acc = b;
#pragma unroll
        for (int k = 0; k < 64; ++k) {
            float xv = __shfl(x, k);
            acc = fmaf(xv, sW[k * 64 + lane], acc);
        }
        acc = (acc >= 0.f) ? acc : 0.01f * acc;
        msg[n * 64 + lane] = acc;
    }
}

extern "C" void kernel_launch(void* const* d_in, const int* in_sizes, int n_in,
                              void* d_out, int out_size, void* d_ws, size_t ws_size,
                              hipStream_t stream) {
    const float* node1 = (const float*)d_in[0];
    const int* seg1 = (const int*)d_in[1];
    // d_in[2] = idx_j1 (unused by reference)
    const float* node2 = (const float*)d_in[3];
    const int* seg2 = (const int*)d_in[4];
    // d_in[5] = idx_j2 (unused)
    const float* Wk = (const float*)d_in[6];
    const float* Wv = (const float*)d_in[7];
    const float* Wo = (const float*)d_in[8];
    const float* bo = (const float*)d_in[9];

    int n1 = in_sizes[0] / 64;
    int n2 = in_sizes[3] / 64;
    int E = in_sizes[1];

    // output layout
    float* out = (float*)d_out;
    float* msg1 = out;                       // n1*64
    float* msg2 = msg1 + (long)n1 * 64;      // n2*64
    float* e1 = msg2 + (long)n2 * 64;        // E
    float* e2 = e1 + E;                      // E

    // workspace layout
    float* ws = (float*)d_ws;
    float* K1 = ws;                          // n1*64
    float* V1 = K1 + (long)n1 * 64;          // n1*64
    float* K2 = V1 + (long)n1 * 64;          // n2*64
    float* V2 = K2 + (long)n2 * 64;          // n2*64
    float* trans = V2 + (long)n2 * 64;       // E
    unsigned* m1k = (unsigned*)(trans + E);  // n1
    unsigned* m2k = m1k + n1;                // n2
    float* s1 = (float*)(m2k + n2);          // n1
    float* s2 = s1 + n1;                     // n2

    const float invT = 1.0f / sqrtf(64.0f);

    // 0: init
    {
        int total = ((n1 > n2 ? n1 : n2)) * 64;
        int blocks = (total + 255) / 256;
        init_kernel<<<blocks, 256, 0, stream>>>(m1k, m2k, s1, s2, msg1, msg2, n1, n2);
    }
    // 1: projections
    proj_kernel<<<(n1 + 3) / 4, 256, 0, stream>>>(node1, n1, Wk, Wv, K1, V1);
    proj_kernel<<<(n2 + 3) / 4, 256, 0, stream>>>(node2, n2, Wk, Wv, K2, V2);
    // 2: logits + segment max
    {
        long threads = (long)E * 16;
        int blocks = (int)((threads + 255) / 256);
        logit_kernel<<<blocks, 256, 0, stream>>>(K1, K2, seg1, seg2, trans, m1k, m2k, E);
    }
    // 3: exp + segment sum
    exp_kernel<<<(E + 255) / 256, 256, 0, stream>>>(trans, seg1, seg2, m1k, m2k,
                                                    s1, s2, e1, e2, E, invT);
    // 4: normalize + scatter messages
    {
        long threads = (long)E * 16;
        int blocks = (int)((threads + 255) / 256);
        scatter_kernel<<<blocks, 256, 0, stream>>>(V1, V2, seg1, seg2, s1, s2,
                                                   e1, e2, msg1, msg2, E);
    }
    // 5: output projection + activation (in place on msg regions)
    out_kernel<<<(n1 + 3) / 4, 256, 0, stream>>>(msg1, n1, Wo, bo);
    out_kernel<<<(n2 + 3) / 4, 256, 0, stream>>>(msg2, n2, Wo, bo);
}

// Round 2
// 661.083 us; speedup vs baseline: 3.0939x; 3.0939x over previous
//
#include <hip/hip_runtime.h>
#include <math.h>

// ---------- 0: zero degree counters ----------
__global__ void zero_deg_kernel(int* d1, int* d2, int n1, int n2) {
    int i = blockIdx.x * blockDim.x + threadIdx.x;
    if (i < n1) d1[i] = 0;
    if (i < n2) d2[i] = 0;
}

// ---------- 1: K/V projection: K = X@Wk, V = X@Wv ----------
__global__ void proj_kernel(const float* __restrict__ X, int N,
                            const float* __restrict__ Wk,
                            const float* __restrict__ Wv,
                            float* __restrict__ K, float* __restrict__ V) {
    __shared__ float sWk[64 * 64];
    __shared__ float sWv[64 * 64];
    int tid = threadIdx.x;
    for (int i = tid; i < 4096; i += blockDim.x) { sWk[i] = Wk[i]; sWv[i] = Wv[i]; }
    __syncthreads();
    int wave = tid >> 6, lane = tid & 63;
    int wpb = blockDim.x >> 6;
    for (int n = blockIdx.x * wpb + wave; n < N; n += gridDim.x * wpb) {
        float x = X[n * 64 + lane];
        float ak = 0.f, av = 0.f;
#pragma unroll
        for (int k = 0; k < 64; ++k) {
            float xv = __shfl(x, k);
            ak = fmaf(xv, sWk[k * 64 + lane], ak);
            av = fmaf(xv, sWv[k * 64 + lane], av);
        }
        K[n * 64 + lane] = ak;
        V[n * 64 + lane] = av;
    }
}

// ---------- 2: edge logits (no atomics) ----------
__global__ void logit_kernel(const float* __restrict__ K1, const float* __restrict__ K2,
                             const int* __restrict__ seg1, const int* __restrict__ seg2,
                             float* __restrict__ trans, int E) {
    int tid = blockIdx.x * blockDim.x + threadIdx.x;
    int e = tid >> 4, g = tid & 15;
    if (e >= E) return;
    int i1 = seg1[e], i2 = seg2[e];
    float4 a = ((const float4*)(K1 + (long)i1 * 64))[g];
    float4 b = ((const float4*)(K2 + (long)i2 * 64))[g];
    float d = a.x * b.x + a.y * b.y + a.z * b.z + a.w * b.w;
    d += __shfl_xor(d, 1);
    d += __shfl_xor(d, 2);
    d += __shfl_xor(d, 4);
    d += __shfl_xor(d, 8);
    if (g == 0) trans[e] = d;
}

// ---------- 3: degree histogram ----------
__global__ void hist_kernel(const int* __restrict__ seg1, const int* __restrict__ seg2,
                            int* deg1, int* deg2, int E) {
    int e = blockIdx.x * blockDim.x + threadIdx.x;
    if (e >= E) return;
    atomicAdd(&deg1[seg1[e]], 1);
    atomicAdd(&deg2[seg2[e]], 1);
}

// ---------- 4: exclusive scan (block 0 -> side1, block 1 -> side2) ----------
__global__ void scan2_kernel(const int* __restrict__ d1, int* __restrict__ c1, int n1,
                             const int* __restrict__ d2, int* __restrict__ c2, int n2) {
    const int* deg = blockIdx.x ? d2 : d1;
    int* cur = blockIdx.x ? c2 : c1;
    int n = blockIdx.x ? n2 : n1;
    __shared__ int tmp[1024];
    __shared__ int s_carry;
    int t = threadIdx.x;
    if (t == 0) s_carry = 0;
    __syncthreads();
    for (int base = 0; base < n; base += 1024) {
        int idx = base + t;
        int v = (idx < n) ? deg[idx] : 0;
        tmp[t] = v;
        __syncthreads();
        for (int off = 1; off < 1024; off <<= 1) {
            int x = (t >= off) ? tmp[t - off] : 0;
            __syncthreads();
            tmp[t] += x;
            __syncthreads();
        }
        int excl = tmp[t] - v + s_carry;
        if (idx < n) cur[idx] = excl;
        __syncthreads();
        if (t == 0) s_carry += tmp[1023];
        __syncthreads();
    }
}

// ---------- 5: bin edge ids into CSR lists ----------
__global__ void bin_kernel(const int* __restrict__ seg1, const int* __restrict__ seg2,
                           int* cur1, int* cur2,
                           int* __restrict__ el1, int* __restrict__ el2, int E) {
    int e = blockIdx.x * blockDim.x + threadIdx.x;
    if (e >= E) return;
    int p1 = atomicAdd(&cur1[seg1[e]], 1);
    el1[p1] = e;
    int p2 = atomicAdd(&cur2[seg2[e]], 1);
    el2[p2] = e;
}

// ---------- 6: per-node softmax + gather-accumulate ----------
// After bin_kernel, cur[i] == start[i] + deg[i] (end offset).
__global__ void gather_kernel(int N, const int* __restrict__ cur, const int* __restrict__ deg,
                              const int* __restrict__ el, const float* __restrict__ trans,
                              const int* __restrict__ segOther, const float* __restrict__ Vother,
                              float* __restrict__ e_out, float* __restrict__ msg_out,
                              float invT) {
    int tid = threadIdx.x;
    int wave = tid >> 6, lane = tid & 63;
    int wpb = blockDim.x >> 6;
    int node = blockIdx.x * wpb + wave;
    if (node >= N) return;
    int d = deg[node];
    int start = cur[node] - d;
    float acc = 0.f;
    if (d > 0) {
        // pass A: segment max
        float m = -INFINITY;
        for (int k = lane; k < d; k += 64) m = fmaxf(m, trans[el[start + k]]);
        m = fmaxf(m, __shfl_xor(m, 1));
        m = fmaxf(m, __shfl_xor(m, 2));
        m = fmaxf(m, __shfl_xor(m, 4));
        m = fmaxf(m, __shfl_xor(m, 8));
        m = fmaxf(m, __shfl_xor(m, 16));
        m = fmaxf(m, __shfl_xor(m, 32));
        // pass B: denominator
        float s = 0.f;
        for (int k = lane; k < d; k += 64) s += __expf((trans[el[start + k]] - m) * invT);
        s += __shfl_xor(s, 1);
        s += __shfl_xor(s, 2);
        s += __shfl_xor(s, 4);
        s += __shfl_xor(s, 8);
        s += __shfl_xor(s, 16);
        s += __shfl_xor(s, 32);
        float inv = 1.f / (s + 1e-8f);
        // pass C: normalize, write edge weights, accumulate w * V[other]
        for (int base = 0; base < d; base += 64) {
            int k = base + lane;
            float w = 0.f;
            int j = 0;
            if (k < d) {
                int e = el[start + k];
                w = __expf((trans[e] - m) * invT) * inv;
                e_out[e] = w;
                j = segOther[e];
            }
            int cnt = (d - base < 64) ? (d - base) : 64;
            for (int q = 0; q < cnt; ++q) {
                float wq = __shfl(w, q);
                int jq = __shfl(j, q);
                acc = fmaf(wq, Vother[(long)jq * 64 + lane], acc);
            }
        }
    }
    msg_out[(long)node * 64 + lane] = acc;
}

// ---------- 7: out GEMM + bias + leaky relu (in place) ----------
__global__ void out_kernel(float* __restrict__ msg, int N,
                           const float* __restrict__ Wo,
                           const float* __restrict__ bo) {
    __shared__ float sW[64 * 64];
    int tid = threadIdx.x;
    for (int i = tid; i < 4096; i += blockDim.x) sW[i] = Wo[i];
    __syncthreads();
    int wave = tid >> 6, lane = tid & 63;
    int wpb = blockDim.x >> 6;
    float b = bo[lane];
    for (int n = blockIdx.x * wpb + wave; n < N; n += gridDim.x * wpb) {
        float x = msg[n * 64 + lane];
        float acc = b;
#pragma unroll
        for (int k = 0; k < 64; ++k) {
            float xv = __shfl(x, k);
            acc = fmaf(xv, sW[k * 64 + lane], acc);
        }
        acc = (acc >= 0.f) ? acc : 0.01f * acc;
        msg[n * 64 + lane] = acc;
    }
}

extern "C" void kernel_launch(void* const* d_in, const int* in_sizes, int n_in,
                              void* d_out, int out_size, void* d_ws, size_t ws_size,
                              hipStream_t stream) {
    const float* node1 = (const float*)d_in[0];
    const int* seg1 = (const int*)d_in[1];
    // d_in[2] = idx_j1 (unused by reference)
    const float* node2 = (const float*)d_in[3];
    const int* seg2 = (const int*)d_in[4];
    // d_in[5] = idx_j2 (unused)
    const float* Wk = (const float*)d_in[6];
    const float* Wv = (const float*)d_in[7];
    const float* Wo = (const float*)d_in[8];
    const float* bo = (const float*)d_in[9];

    int n1 = in_sizes[0] / 64;
    int n2 = in_sizes[3] / 64;
    int E = in_sizes[1];

    // output layout
    float* out = (float*)d_out;
    float* msg1 = out;                       // n1*64
    float* msg2 = msg1 + (long)n1 * 64;      // n2*64
    float* e1 = msg2 + (long)n2 * 64;        // E
    float* e2 = e1 + E;                      // E

    // workspace layout
    float* ws = (float*)d_ws;
    float* K1 = ws;                          // n1*64  (aliased by el1 after logit)
    float* V1 = K1 + (long)n1 * 64;          // n1*64
    float* K2 = V1 + (long)n1 * 64;          // n2*64  (aliased by el2 after logit)
    float* V2 = K2 + (long)n2 * 64;          // n2*64
    float* trans = V2 + (long)n2 * 64;       // E
    int* deg1 = (int*)(trans + E);           // n1
    int* deg2 = deg1 + n1;                   // n2
    int* cur1 = deg2 + n2;                   // n1
    int* cur2 = cur1 + n1;                   // n2
    // edge lists alias dead K buffers (E <= n*64 holds for this problem)
    int* el1 = (int*)K1;                     // E
    int* el2 = (int*)K2;                     // E

    const float invT = 1.0f / sqrtf(64.0f);

    int nmax = n1 > n2 ? n1 : n2;

    // 0: zero degree counters
    zero_deg_kernel<<<(nmax + 255) / 256, 256, 0, stream>>>(deg1, deg2, n1, n2);
    // 1: projections
    proj_kernel<<<(n1 + 3) / 4, 256, 0, stream>>>(node1, n1, Wk, Wv, K1, V1);
    proj_kernel<<<(n2 + 3) / 4, 256, 0, stream>>>(node2, n2, Wk, Wv, K2, V2);
    // 2: logits
    {
        long threads = (long)E * 16;
        int blocks = (int)((threads + 255) / 256);
        logit_kernel<<<blocks, 256, 0, stream>>>(K1, K2, seg1, seg2, trans, E);
    }
    // 3: degree histogram
    hist_kernel<<<(E + 255) / 256, 256, 0, stream>>>(seg1, seg2, deg1, deg2, E);
    // 4: exclusive scan -> cur holds start offsets
    scan2_kernel<<<2, 1024, 0, stream>>>(deg1, cur1, n1, deg2, cur2, n2);
    // 5: bin edges into CSR lists (cur becomes end offsets)
    bin_kernel<<<(E + 255) / 256, 256, 0, stream>>>(seg1, seg2, cur1, cur2, el1, el2, E);
    // 6: per-node softmax + gather
    gather_kernel<<<(n1 + 3) / 4, 256, 0, stream>>>(n1, cur1, deg1, el1, trans,
                                                    seg2, V2, e1, msg1, invT);
    gather_kernel<<<(n2 + 3) / 4, 256, 0, stream>>>(n2, cur2, deg2, el2, trans,
                                                    seg1, V1, e2, msg2, invT);
    // 7: output projection + activation (in place on msg regions)
    out_kernel<<<(n1 + 3) / 4, 256, 0, stream>>>(msg1, n1, Wo, bo);
    out_kernel<<<(n2 + 3) / 4, 256, 0, stream>>>(msg2, n2, Wo, bo);
}

// Round 3
// 442.766 us; speedup vs baseline: 4.6194x; 1.4931x over previous
//
#include <hip/hip_runtime.h>
#include <math.h>

#define BSH 7              // 128 nodes per bucket
#define BSZ (1 << BSH)
#define MAXNB 256          // max buckets per side
#define PT_TILE 4096       // edges per partition block

// ---------- projections: K = X@Wk, V = X@Wv ----------
__global__ void proj_kernel(const float* __restrict__ X, int N,
                            const float* __restrict__ Wk,
                            const float* __restrict__ Wv,
                            float* __restrict__ K, float* __restrict__ V) {
    __shared__ float sWk[64 * 64];
    __shared__ float sWv[64 * 64];
    int tid = threadIdx.x;
    for (int i = tid; i < 4096; i += blockDim.x) { sWk[i] = Wk[i]; sWv[i] = Wv[i]; }
    __syncthreads();
    int wave = tid >> 6, lane = tid & 63;
    int wpb = blockDim.x >> 6;
    for (int n = blockIdx.x * wpb + wave; n < N; n += gridDim.x * wpb) {
        float x = X[n * 64 + lane];
        float ak = 0.f, av = 0.f;
#pragma unroll
        for (int k = 0; k < 64; ++k) {
            float xv = __shfl(x, k);
            ak = fmaf(xv, sWk[k * 64 + lane], ak);
            av = fmaf(xv, sWv[k * 64 + lane], av);
        }
        K[n * 64 + lane] = ak;
        V[n * 64 + lane] = av;
    }
}

// ---------- edge logits ----------
__global__ void logit_kernel(const float* __restrict__ K1, const float* __restrict__ K2,
                             const int* __restrict__ seg1, const int* __restrict__ seg2,
                             float* __restrict__ trans, int E) {
    int tid = blockIdx.x * blockDim.x + threadIdx.x;
    int e = tid >> 4, g = tid & 15;
    if (e >= E) return;
    int i1 = seg1[e], i2 = seg2[e];
    float4 a = ((const float4*)(K1 + (long)i1 * 64))[g];
    float4 b = ((const float4*)(K2 + (long)i2 * 64))[g];
    float d = a.x * b.x + a.y * b.y + a.z * b.z + a.w * b.w;
    d += __shfl_xor(d, 1);
    d += __shfl_xor(d, 2);
    d += __shfl_xor(d, 4);
    d += __shfl_xor(d, 8);
    if (g == 0) trans[e] = d;
}

// ---------- fast path: bucket histogram (LDS-aggregated) ----------
__global__ void zero_small_kernel(int* b1, int* b2, int nb1, int nb2) {
    int i = threadIdx.x;
    if (i < nb1) b1[i] = 0;
    if (i < nb2) b2[i] = 0;
}

__global__ void bucket_count_kernel(const int* __restrict__ seg1, const int* __restrict__ seg2,
                                    int E, int* bcnt1, int* bcnt2, int nb1, int nb2) {
    __shared__ int c1[MAXNB], c2[MAXNB];
    int tid = threadIdx.x;
    for (int i = tid; i < MAXNB; i += blockDim.x) { c1[i] = 0; c2[i] = 0; }
    __syncthreads();
    for (int i = blockIdx.x * blockDim.x + tid; i < E; i += gridDim.x * blockDim.x) {
        atomicAdd(&c1[seg1[i] >> BSH], 1);
        atomicAdd(&c2[seg2[i] >> BSH], 1);
    }
    __syncthreads();
    for (int i = tid; i < nb1; i += blockDim.x) if (c1[i]) atomicAdd(&bcnt1[i], c1[i]);
    for (int i = tid; i < nb2; i += blockDim.x) if (c2[i]) atomicAdd(&bcnt2[i], c2[i]);
}

// ---------- fast path: scan bucket counts (1 block, 256 threads) ----------
__global__ void bucket_scan_kernel(const int* __restrict__ bcnt1, const int* __restrict__ bcnt2,
                                   int* bb1, int* bb2, int* bcur1, int* bcur2,
                                   int nb1, int nb2, int E) {
    __shared__ int tmp[MAXNB];
    int t = threadIdx.x;
    int v1 = (t < nb1) ? bcnt1[t] : 0;
    tmp[t] = v1;
    __syncthreads();
    for (int off = 1; off < MAXNB; off <<= 1) {
        int x = (t >= off) ? tmp[t - off] : 0;
        __syncthreads();
        tmp[t] += x;
        __syncthreads();
    }
    if (t < nb1) { int excl = tmp[t] - v1; bb1[t] = excl; bcur1[t] = excl; }
    if (t == 0) bb1[nb1] = E;
    __syncthreads();
    int v2 = (t < nb2) ? bcnt2[t] : 0;
    tmp[t] = v2;
    __syncthreads();
    for (int off = 1; off < MAXNB; off <<= 1) {
        int x = (t >= off) ? tmp[t - off] : 0;
        __syncthreads();
        tmp[t] += x;
        __syncthreads();
    }
    if (t < nb2) { int excl = tmp[t] - v2; bb2[t] = excl; bcur2[t] = excl; }
    if (t == 0) bb2[nb2] = E;
}

// ---------- fast path: partition edges into bucket-contiguous regions ----------
__global__ void partition_kernel(const int* __restrict__ seg1, const int* __restrict__ seg2, int E,
                                 int* bcur1, int* bcur2,
                                 unsigned* __restrict__ tmp1, unsigned* __restrict__ tmp2) {
    __shared__ int c1[MAXNB], c2[MAXNB];
    int tid = threadIdx.x;
    int base = blockIdx.x * PT_TILE;
    int end = base + PT_TILE;
    if (end > E) end = E;
    for (int i = tid; i < MAXNB; i += blockDim.x) { c1[i] = 0; c2[i] = 0; }
    __syncthreads();
    for (int i = base + tid; i < end; i += blockDim.x) {
        atomicAdd(&c1[seg1[i] >> BSH], 1);
        atomicAdd(&c2[seg2[i] >> BSH], 1);
    }
    __syncthreads();
    // reserve global space per bucket; c[] becomes the global write cursor
    for (int i = tid; i < MAXNB; i += blockDim.x) {
        int n = c1[i]; c1[i] = n ? atomicAdd(&bcur1[i], n) : 0;
        n = c2[i];     c2[i] = n ? atomicAdd(&bcur2[i], n) : 0;
    }
    __syncthreads();
    for (int i = base + tid; i < end; i += blockDim.x) {
        int s1 = seg1[i];
        int p = atomicAdd(&c1[s1 >> BSH], 1);
        tmp1[p] = ((unsigned)(s1 & (BSZ - 1)) << 20) | (unsigned)i;
        int s2 = seg2[i];
        int q = atomicAdd(&c2[s2 >> BSH], 1);
        tmp2[q] = ((unsigned)(s2 & (BSZ - 1)) << 20) | (unsigned)i;
    }
}

// ---------- fast path: per-bucket exact binning; also emits cur (start) + deg ----------
__global__ void bin2_kernel(const unsigned* __restrict__ tmp, const int* __restrict__ bb,
                            int n, int* __restrict__ cur, int* __restrict__ deg,
                            int* __restrict__ el) {
    __shared__ int cnt[BSZ];
    __shared__ int off[BSZ];
    __shared__ int sc[BSZ];
    int b = blockIdx.x;
    int tid = threadIdx.x;
    int node0 = b << BSH;
    int s = bb[b], e_end = bb[b + 1];
    for (int i = tid; i < BSZ; i += blockDim.x) cnt[i] = 0;
    __syncthreads();
    for (int i = s + tid; i < e_end; i += blockDim.x) atomicAdd(&cnt[tmp[i] >> 20], 1);
    __syncthreads();
    if (tid < BSZ) sc[tid] = cnt[tid];
    __syncthreads();
    for (int o = 1; o < BSZ; o <<= 1) {
        int x = (tid >= o && tid < BSZ) ? sc[tid - o] : 0;
        __syncthreads();
        if (tid < BSZ) sc[tid] += x;
        __syncthreads();
    }
    if (tid < BSZ) {
        int excl = sc[tid] - cnt[tid] + s;
        off[tid] = excl;
        int node = node0 + tid;
        if (node < n) { cur[node] = excl; deg[node] = cnt[tid]; }
    }
    __syncthreads();
    for (int i = s + tid; i < e_end; i += blockDim.x) {
        unsigned v = tmp[i];
        int pos = atomicAdd(&off[v >> 20], 1);
        el[pos] = (int)(v & 0xFFFFFu);
    }
}

// ---------- fallback path kernels (R2-proven) ----------
__global__ void zero_deg_kernel(int* d1, int* d2, int n1, int n2) {
    int i = blockIdx.x * blockDim.x + threadIdx.x;
    if (i < n1) d1[i] = 0;
    if (i < n2) d2[i] = 0;
}
__global__ void hist_kernel(const int* __restrict__ seg1, const int* __restrict__ seg2,
                            int* deg1, int* deg2, int E) {
    int e = blockIdx.x * blockDim.x + threadIdx.x;
    if (e >= E) return;
    atomicAdd(&deg1[seg1[e]], 1);
    atomicAdd(&deg2[seg2[e]], 1);
}
__global__ void scan2_kernel(const int* __restrict__ d1, int* __restrict__ c1, int n1,
                             const int* __restrict__ d2, int* __restrict__ c2, int n2) {
    const int* deg = blockIdx.x ? d2 : d1;
    int* cur = blockIdx.x ? c2 : c1;
    int n = blockIdx.x ? n2 : n1;
    __shared__ int tmp[1024];
    __shared__ int s_carry;
    int t = threadIdx.x;
    if (t == 0) s_carry = 0;
    __syncthreads();
    for (int base = 0; base < n; base += 1024) {
        int idx = base + t;
        int v = (idx < n) ? deg[idx] : 0;
        tmp[t] = v;
        __syncthreads();
        for (int off = 1; off < 1024; off <<= 1) {
            int x = (t >= off) ? tmp[t - off] : 0;
            __syncthreads();
            tmp[t] += x;
            __syncthreads();
        }
        int excl = tmp[t] - v + s_carry;
        if (idx < n) cur[idx] = excl;
        __syncthreads();
        if (t == 0) s_carry += tmp[1023];
        __syncthreads();
    }
}
__global__ void bin_kernel(const int* __restrict__ seg1, const int* __restrict__ seg2,
                           int* cur1, int* cur2,
                           int* __restrict__ el1, int* __restrict__ el2, int E) {
    int e = blockIdx.x * blockDim.x + threadIdx.x;
    if (e >= E) return;
    int p1 = atomicAdd(&cur1[seg1[e]], 1);
    el1[p1] = e;
    int p2 = atomicAdd(&cur2[seg2[e]], 1);
    el2[p2] = e;
}

// ---------- gather + softmax + fused output projection ----------
// startConv=1: cur holds start offsets; startConv=0: cur holds end offsets.
__global__ void gather_out_kernel(int N, const int* __restrict__ cur, const int* __restrict__ deg,
                                  const int* __restrict__ el, const float* __restrict__ trans,
                                  const int* __restrict__ segOther, const float* __restrict__ Vother,
                                  float* __restrict__ e_out, float* __restrict__ msg_out,
                                  const float* __restrict__ Wo, const float* __restrict__ bo,
                                  float invT, int startConv) {
    __shared__ float sW[64 * 64];
    int tid = threadIdx.x;
    for (int i = tid; i < 4096; i += blockDim.x) sW[i] = Wo[i];
    __syncthreads();
    int wave = tid >> 6, lane = tid & 63;
    int wpb = blockDim.x >> 6;
    int node = blockIdx.x * wpb + wave;
    if (node >= N) return;
    int d = deg[node];
    int start = startConv ? cur[node] : (cur[node] - d);
    float acc = 0.f;
    if (d > 0) {
        float m = -INFINITY;
        for (int k = lane; k < d; k += 64) m = fmaxf(m, trans[el[start + k]]);
        m = fmaxf(m, __shfl_xor(m, 1));
        m = fmaxf(m, __shfl_xor(m, 2));
        m = fmaxf(m, __shfl_xor(m, 4));
        m = fmaxf(m, __shfl_xor(m, 8));
        m = fmaxf(m, __shfl_xor(m, 16));
        m = fmaxf(m, __shfl_xor(m, 32));
        float s = 0.f;
        for (int k = lane; k < d; k += 64) s += __expf((trans[el[start + k]] - m) * invT);
        s += __shfl_xor(s, 1);
        s += __shfl_xor(s, 2);
        s += __shfl_xor(s, 4);
        s += __shfl_xor(s, 8);
        s += __shfl_xor(s, 16);
        s += __shfl_xor(s, 32);
        float inv = 1.f / (s + 1e-8f);
        for (int base = 0; base < d; base += 64) {
            int k = base + lane;
            float w = 0.f;
            int j = 0;
            if (k < d) {
                int e = el[start + k];
                w = __expf((trans[e] - m) * invT) * inv;
                e_out[e] = w;
                j = segOther[e];
            }
            int cnt = (d - base < 64) ? (d - base) : 64;
            for (int q = 0; q < cnt; ++q) {
                float wq = __shfl(w, q);
                int jq = __shfl(j, q);
                acc = fmaf(wq, Vother[(long)jq * 64 + lane], acc);
            }
        }
    }
    // fused output projection + bias + leaky relu
    float o = bo[lane];
#pragma unroll
    for (int k = 0; k < 64; ++k) {
        float xv = __shfl(acc, k);
        o = fmaf(xv, sW[k * 64 + lane], o);
    }
    o = (o >= 0.f) ? o : 0.01f * o;
    msg_out[(long)node * 64 + lane] = o;
}

extern "C" void kernel_launch(void* const* d_in, const int* in_sizes, int n_in,
                              void* d_out, int out_size, void* d_ws, size_t ws_size,
                              hipStream_t stream) {
    const float* node1 = (const float*)d_in[0];
    const int* seg1 = (const int*)d_in[1];
    const float* node2 = (const float*)d_in[3];
    const int* seg2 = (const int*)d_in[4];
    const float* Wk = (const float*)d_in[6];
    const float* Wv = (const float*)d_in[7];
    const float* Wo = (const float*)d_in[8];
    const float* bo = (const float*)d_in[9];

    int n1 = in_sizes[0] / 64;
    int n2 = in_sizes[3] / 64;
    int E = in_sizes[1];

    // output layout
    float* out = (float*)d_out;
    float* msg1 = out;
    float* msg2 = msg1 + (long)n1 * 64;
    float* e1 = msg2 + (long)n2 * 64;
    float* e2 = e1 + E;

    const float invT = 1.0f / sqrtf(64.0f);
    int nb1 = (n1 + BSZ - 1) >> BSH;
    int nb2 = (n2 + BSZ - 1) >> BSH;

    // common workspace prefix
    float* ws = (float*)d_ws;
    float* K1 = ws;                          // n1*64
    float* V1 = K1 + (long)n1 * 64;          // n1*64
    float* K2 = V1 + (long)n1 * 64;          // n2*64
    float* V2 = K2 + (long)n2 * 64;          // n2*64
    float* trans = V2 + (long)n2 * 64;       // E

    // fast-path layout (el gets fresh space; tmp aliases dead K buffers)
    long fp_words = (long)n1 * 64 * 2 + (long)n2 * 64 * 2 + E   // K/V/trans prefix
                  + (long)E * 2                                  // el1, el2
                  + 2L * (n1 + n2)                               // deg, cur
                  + 2L * (nb1 + 1) + 2L * (nb2 + 1)              // bb + bcur
                  + (nb1 + nb2);                                 // bcnt
    bool fast = (E <= (1 << 20)) && (nb1 <= MAXNB) && (nb2 <= MAXNB)
             && ((long)E <= (long)n1 * 64) && ((long)E <= (long)n2 * 64)
             && ((size_t)fp_words * 4 <= ws_size);

    // shared projections + logits
    proj_kernel<<<(n1 + 3) / 4, 256, 0, stream>>>(node1, n1, Wk, Wv, K1, V1);
    proj_kernel<<<(n2 + 3) / 4, 256, 0, stream>>>(node2, n2, Wk, Wv, K2, V2);
    {
        long threads = (long)E * 16;
        int blocks = (int)((threads + 255) / 256);
        logit_kernel<<<blocks, 256, 0, stream>>>(K1, K2, seg1, seg2, trans, E);
    }

    if (fast) {
        int* el1 = (int*)(trans + E);        // E
        int* el2 = el1 + E;                  // E
        int* deg1 = el2 + E;                 // n1
        int* deg2 = deg1 + n1;               // n2
        int* cur1 = deg2 + n2;               // n1
        int* cur2 = cur1 + n1;               // n2
        int* bb1 = cur2 + n2;                // nb1+1
        int* bb2 = bb1 + nb1 + 1;            // nb2+1
        int* bcur1 = bb2 + nb2 + 1;          // nb1
        int* bcur2 = bcur1 + nb1;            // nb2
        int* bcnt1 = bcur2 + nb2;            // nb1
        int* bcnt2 = bcnt1 + nb1;            // nb2
        unsigned* tmp1 = (unsigned*)K1;      // E (K dead after logit)
        unsigned* tmp2 = (unsigned*)K2;      // E

        zero_small_kernel<<<1, 256, 0, stream>>>(bcnt1, bcnt2, nb1, nb2);
        bucket_count_kernel<<<512, 256, 0, stream>>>(seg1, seg2, E, bcnt1, bcnt2, nb1, nb2);
        bucket_scan_kernel<<<1, MAXNB, 0, stream>>>(bcnt1, bcnt2, bb1, bb2, bcur1, bcur2,
                                                    nb1, nb2, E);
        partition_kernel<<<(E + PT_TILE - 1) / PT_TILE, 256, 0, stream>>>(
            seg1, seg2, E, bcur1, bcur2, tmp1, tmp2);
        bin2_kernel<<<nb1, 256, 0, stream>>>(tmp1, bb1, n1, cur1, deg1, el1);
        bin2_kernel<<<nb2, 256, 0, stream>>>(tmp2, bb2, n2, cur2, deg2, el2);

        gather_out_kernel<<<(n1 + 3) / 4, 256, 0, stream>>>(
            n1, cur1, deg1, el1, trans, seg2, V2, e1, msg1, Wo, bo, invT, 1);
        gather_out_kernel<<<(n2 + 3) / 4, 256, 0, stream>>>(
            n2, cur2, deg2, el2, trans, seg1, V1, e2, msg2, Wo, bo, invT, 1);
    } else {
        // fallback: R2-proven path (el aliases dead K buffers)
        int* deg1 = (int*)(trans + E);       // n1
        int* deg2 = deg1 + n1;               // n2
        int* cur1 = deg2 + n2;               // n1
        int* cur2 = cur1 + n1;               // n2
        int* el1 = (int*)K1;                 // E
        int* el2 = (int*)K2;                 // E
        int nmax = n1 > n2 ? n1 : n2;

        zero_deg_kernel<<<(nmax + 255) / 256, 256, 0, stream>>>(deg1, deg2, n1, n2);
        hist_kernel<<<(E + 255) / 256, 256, 0, stream>>>(seg1, seg2, deg1, deg2, E);
        scan2_kernel<<<2, 1024, 0, stream>>>(deg1, cur1, n1, deg2, cur2, n2);
        bin_kernel<<<(E + 255) / 256, 256, 0, stream>>>(seg1, seg2, cur1, cur2, el1, el2, E);

        gather_out_kernel<<<(n1 + 3) / 4, 256, 0, stream>>>(
            n1, cur1, deg1, el1, trans, seg2, V2, e1, msg1, Wo, bo, invT, 0);
        gather_out_kernel<<<(n2 + 3) / 4, 256, 0, stream>>>(
            n2, cur2, deg2, el2, trans, seg1, V1, e2, msg2, Wo, bo, invT, 0);
    }
}

// Round 4
// 397.749 us; speedup vs baseline: 5.1422x; 1.1132x over previous
//
#include <hip/hip_runtime.h>
#include <math.h>

#define BSH 7              // 128 nodes per bucket
#define BSZ (1 << BSH)
#define MAXNB 256          // max buckets per side
#define PT_TILE 4096       // edges per partition block

__device__ __forceinline__ float readlane_f(float v, int l) {
    return __uint_as_float((unsigned)__builtin_amdgcn_readlane((int)__float_as_uint(v), l));
}
__device__ __forceinline__ int readlane_i(int v, int l) {
    return __builtin_amdgcn_readlane(v, l);
}

// ---------- projections: K = X@Wk, V = X@Wv ----------
__global__ void proj_kernel(const float* __restrict__ X, int N,
                            const float* __restrict__ Wk,
                            const float* __restrict__ Wv,
                            float* __restrict__ K, float* __restrict__ V) {
    __shared__ float sWk[64 * 64];
    __shared__ float sWv[64 * 64];
    int tid = threadIdx.x;
    for (int i = tid; i < 4096; i += blockDim.x) { sWk[i] = Wk[i]; sWv[i] = Wv[i]; }
    __syncthreads();
    int wave = tid >> 6, lane = tid & 63;
    int wpb = blockDim.x >> 6;
    for (int n = blockIdx.x * wpb + wave; n < N; n += gridDim.x * wpb) {
        float x = X[n * 64 + lane];
        float ak = 0.f, av = 0.f;
#pragma unroll
        for (int k = 0; k < 64; ++k) {
            float xv = __shfl(x, k);
            ak = fmaf(xv, sWk[k * 64 + lane], ak);
            av = fmaf(xv, sWv[k * 64 + lane], av);
        }
        K[n * 64 + lane] = ak;
        V[n * 64 + lane] = av;
    }
}

// ---------- edge logits ----------
__global__ void logit_kernel(const float* __restrict__ K1, const float* __restrict__ K2,
                             const int* __restrict__ seg1, const int* __restrict__ seg2,
                             float* __restrict__ trans, int E) {
    int tid = blockIdx.x * blockDim.x + threadIdx.x;
    int e = tid >> 4, g = tid & 15;
    if (e >= E) return;
    int i1 = seg1[e], i2 = seg2[e];
    float4 a = ((const float4*)(K1 + (long)i1 * 64))[g];
    float4 b = ((const float4*)(K2 + (long)i2 * 64))[g];
    float d = a.x * b.x + a.y * b.y + a.z * b.z + a.w * b.w;
    d += __shfl_xor(d, 1);
    d += __shfl_xor(d, 2);
    d += __shfl_xor(d, 4);
    d += __shfl_xor(d, 8);
    if (g == 0) trans[e] = d;
}

// ---------- fast path: bucket histogram ----------
__global__ void zero_small_kernel(int* b1, int* b2, int nb1, int nb2) {
    int i = threadIdx.x;
    if (i < nb1) b1[i] = 0;
    if (i < nb2) b2[i] = 0;
}

__global__ void bucket_count_kernel(const int* __restrict__ seg1, const int* __restrict__ seg2,
                                    int E, int* bcnt1, int* bcnt2, int nb1, int nb2) {
    __shared__ int c1[MAXNB], c2[MAXNB];
    int tid = threadIdx.x;
    for (int i = tid; i < MAXNB; i += blockDim.x) { c1[i] = 0; c2[i] = 0; }
    __syncthreads();
    for (int i = blockIdx.x * blockDim.x + tid; i < E; i += gridDim.x * blockDim.x) {
        atomicAdd(&c1[seg1[i] >> BSH], 1);
        atomicAdd(&c2[seg2[i] >> BSH], 1);
    }
    __syncthreads();
    for (int i = tid; i < nb1; i += blockDim.x) if (c1[i]) atomicAdd(&bcnt1[i], c1[i]);
    for (int i = tid; i < nb2; i += blockDim.x) if (c2[i]) atomicAdd(&bcnt2[i], c2[i]);
}

// ---------- fast path: scan bucket counts ----------
__global__ void bucket_scan_kernel(const int* __restrict__ bcnt1, const int* __restrict__ bcnt2,
                                   int* bb1, int* bb2, int* bcur1, int* bcur2,
                                   int nb1, int nb2, int E) {
    __shared__ int tmp[MAXNB];
    int t = threadIdx.x;
    int v1 = (t < nb1) ? bcnt1[t] : 0;
    tmp[t] = v1;
    __syncthreads();
    for (int off = 1; off < MAXNB; off <<= 1) {
        int x = (t >= off) ? tmp[t - off] : 0;
        __syncthreads();
        tmp[t] += x;
        __syncthreads();
    }
    if (t < nb1) { int excl = tmp[t] - v1; bb1[t] = excl; bcur1[t] = excl; }
    if (t == 0) bb1[nb1] = E;
    __syncthreads();
    int v2 = (t < nb2) ? bcnt2[t] : 0;
    tmp[t] = v2;
    __syncthreads();
    for (int off = 1; off < MAXNB; off <<= 1) {
        int x = (t >= off) ? tmp[t - off] : 0;
        __syncthreads();
        tmp[t] += x;
        __syncthreads();
    }
    if (t < nb2) { int excl = tmp[t] - v2; bb2[t] = excl; bcur2[t] = excl; }
    if (t == 0) bb2[nb2] = E;
}

// ---------- fast path: partition edges into bucket regions ----------
__global__ void partition_kernel(const int* __restrict__ seg1, const int* __restrict__ seg2, int E,
                                 int* bcur1, int* bcur2,
                                 unsigned* __restrict__ tmp1, unsigned* __restrict__ tmp2) {
    __shared__ int c1[MAXNB], c2[MAXNB];
    int tid = threadIdx.x;
    int base = blockIdx.x * PT_TILE;
    int end = base + PT_TILE;
    if (end > E) end = E;
    for (int i = tid; i < MAXNB; i += blockDim.x) { c1[i] = 0; c2[i] = 0; }
    __syncthreads();
    for (int i = base + tid; i < end; i += blockDim.x) {
        atomicAdd(&c1[seg1[i] >> BSH], 1);
        atomicAdd(&c2[seg2[i] >> BSH], 1);
    }
    __syncthreads();
    for (int i = tid; i < MAXNB; i += blockDim.x) {
        int n = c1[i]; c1[i] = n ? atomicAdd(&bcur1[i], n) : 0;
        n = c2[i];     c2[i] = n ? atomicAdd(&bcur2[i], n) : 0;
    }
    __syncthreads();
    for (int i = base + tid; i < end; i += blockDim.x) {
        int s1 = seg1[i];
        int p = atomicAdd(&c1[s1 >> BSH], 1);
        tmp1[p] = ((unsigned)(s1 & (BSZ - 1)) << 20) | (unsigned)i;
        int s2 = seg2[i];
        int q = atomicAdd(&c2[s2 >> BSH], 1);
        tmp2[q] = ((unsigned)(s2 & (BSZ - 1)) << 20) | (unsigned)i;
    }
}

// ---------- fast path: per-bucket binning -> packed (t, j) CSR records ----------
__global__ void bin2_kernel(const unsigned* __restrict__ tmp, const int* __restrict__ bb,
                            int n, int* __restrict__ cur, int* __restrict__ deg,
                            float2* __restrict__ csr,
                            const float* __restrict__ trans, const int* __restrict__ segO) {
    __shared__ int cnt[BSZ];
    __shared__ int off[BSZ];
    __shared__ int sc[BSZ];
    int b = blockIdx.x;
    int tid = threadIdx.x;
    int node0 = b << BSH;
    int s = bb[b], e_end = bb[b + 1];
    for (int i = tid; i < BSZ; i += blockDim.x) cnt[i] = 0;
    __syncthreads();
    for (int i = s + tid; i < e_end; i += blockDim.x) atomicAdd(&cnt[tmp[i] >> 20], 1);
    __syncthreads();
    if (tid < BSZ) sc[tid] = cnt[tid];
    __syncthreads();
    for (int o = 1; o < BSZ; o <<= 1) {
        int x = (tid >= o && tid < BSZ) ? sc[tid - o] : 0;
        __syncthreads();
        if (tid < BSZ) sc[tid] += x;
        __syncthreads();
    }
    if (tid < BSZ) {
        int excl = sc[tid] - cnt[tid] + s;
        off[tid] = excl;
        int node = node0 + tid;
        if (node < n) { cur[node] = excl; deg[node] = cnt[tid]; }
    }
    __syncthreads();
    for (int i = s + tid; i < e_end; i += blockDim.x) {
        unsigned v = tmp[i];
        int eid = (int)(v & 0xFFFFFu);
        float t = trans[eid];
        int j = segO[eid];
        int pos = atomicAdd(&off[v >> 20], 1);
        csr[pos] = make_float2(t, __int_as_float(j));
    }
}

// ---------- fast path: gather + softmax + fused Wo ----------
__global__ void gather_ms_kernel(int N, const int* __restrict__ cur, const int* __restrict__ deg,
                                 const float2* __restrict__ csr, const float* __restrict__ Vother,
                                 float2* __restrict__ minv, float* __restrict__ msg_out,
                                 const float* __restrict__ Wo, const float* __restrict__ bo,
                                 float invT) {
    __shared__ float sW[64 * 64];
    int tid = threadIdx.x;
    for (int i = tid; i < 4096; i += blockDim.x) sW[i] = Wo[i];
    __syncthreads();
    int wave = tid >> 6, lane = tid & 63;
    int node = blockIdx.x * (blockDim.x >> 6) + wave;
    if (node >= N) return;
    int d = deg[node];
    int start = cur[node];
    float acc = 0.f;
    if (d > 0) {
        float t0 = -INFINITY, t1 = -INFINITY, t2 = -INFINITY;
        int j0 = 0, j1 = 0, j2 = 0;
        if (lane < d)       { float2 r = csr[start + lane];        t0 = r.x; j0 = __float_as_int(r.y); }
        if (lane + 64 < d)  { float2 r = csr[start + lane + 64];   t1 = r.x; j1 = __float_as_int(r.y); }
        if (lane + 128 < d) { float2 r = csr[start + lane + 128];  t2 = r.x; j2 = __float_as_int(r.y); }
        float m = fmaxf(fmaxf(t0, t1), t2);
        for (int k = 192 + lane; k < d; k += 64) m = fmaxf(m, csr[start + k].x);
        m = fmaxf(m, __shfl_xor(m, 1));
        m = fmaxf(m, __shfl_xor(m, 2));
        m = fmaxf(m, __shfl_xor(m, 4));
        m = fmaxf(m, __shfl_xor(m, 8));
        m = fmaxf(m, __shfl_xor(m, 16));
        m = fmaxf(m, __shfl_xor(m, 32));
        float p0 = (lane < d)       ? __expf((t0 - m) * invT) : 0.f;
        float p1 = (lane + 64 < d)  ? __expf((t1 - m) * invT) : 0.f;
        float p2 = (lane + 128 < d) ? __expf((t2 - m) * invT) : 0.f;
        float s = p0 + p1 + p2;
        for (int k = 192 + lane; k < d; k += 64) s += __expf((csr[start + k].x - m) * invT);
        s += __shfl_xor(s, 1);
        s += __shfl_xor(s, 2);
        s += __shfl_xor(s, 4);
        s += __shfl_xor(s, 8);
        s += __shfl_xor(s, 16);
        s += __shfl_xor(s, 32);
        float inv = 1.f / (s + 1e-8f);
        if (lane == 0) minv[node] = make_float2(m, inv);
        float w0 = p0 * inv, w1 = p1 * inv, w2 = p2 * inv;
        int c0 = d < 64 ? d : 64;
#pragma unroll 4
        for (int q = 0; q < c0; ++q)
            acc = fmaf(readlane_f(w0, q), Vother[(long)readlane_i(j0, q) * 64 + lane], acc);
        if (d > 64) {
            int c1 = (d - 64) < 64 ? (d - 64) : 64;
#pragma unroll 4
            for (int q = 0; q < c1; ++q)
                acc = fmaf(readlane_f(w1, q), Vother[(long)readlane_i(j1, q) * 64 + lane], acc);
        }
        if (d > 128) {
            int c2 = (d - 128) < 64 ? (d - 128) : 64;
#pragma unroll 4
            for (int q = 0; q < c2; ++q)
                acc = fmaf(readlane_f(w2, q), Vother[(long)readlane_i(j2, q) * 64 + lane], acc);
        }
        for (int base = 192; base < d; base += 64) {
            int k = base + lane;
            float w = 0.f; int j = 0;
            if (k < d) { float2 r = csr[start + k]; w = __expf((r.x - m) * invT) * inv; j = __float_as_int(r.y); }
            int cc = (d - base) < 64 ? (d - base) : 64;
            for (int q = 0; q < cc; ++q)
                acc = fmaf(readlane_f(w, q), Vother[(long)readlane_i(j, q) * 64 + lane], acc);
        }
    }
    float o = bo[lane];
#pragma unroll
    for (int k = 0; k < 64; ++k)
        o = fmaf(readlane_f(acc, k), sW[k * 64 + lane], o);
    o = (o >= 0.f) ? o : 0.01f * o;
    msg_out[(long)node * 64 + lane] = o;
}

// ---------- fast path: coalesced edge weights ----------
__global__ void edge_w_kernel(const float* __restrict__ trans,
                              const int* __restrict__ seg1, const int* __restrict__ seg2,
                              const float2* __restrict__ minv1, const float2* __restrict__ minv2,
                              float* __restrict__ e1, float* __restrict__ e2,
                              int E, float invT) {
    int e = blockIdx.x * blockDim.x + threadIdx.x;
    if (e >= E) return;
    float t = trans[e];
    float2 a = minv1[seg1[e]];
    float2 b = minv2[seg2[e]];
    e1[e] = __expf((t - a.x) * invT) * a.y;
    e2[e] = __expf((t - b.x) * invT) * b.y;
}

// ---------- fallback path kernels (R2-proven) ----------
__global__ void zero_deg_kernel(int* d1, int* d2, int n1, int n2) {
    int i = blockIdx.x * blockDim.x + threadIdx.x;
    if (i < n1) d1[i] = 0;
    if (i < n2) d2[i] = 0;
}
__global__ void hist_kernel(const int* __restrict__ seg1, const int* __restrict__ seg2,
                            int* deg1, int* deg2, int E) {
    int e = blockIdx.x * blockDim.x + threadIdx.x;
    if (e >= E) return;
    atomicAdd(&deg1[seg1[e]], 1);
    atomicAdd(&deg2[seg2[e]], 1);
}
__global__ void scan2_kernel(const int* __restrict__ d1, int* __restrict__ c1, int n1,
                             const int* __restrict__ d2, int* __restrict__ c2, int n2) {
    const int* deg = blockIdx.x ? d2 : d1;
    int* cur = blockIdx.x ? c2 : c1;
    int n = blockIdx.x ? n2 : n1;
    __shared__ int tmp[1024];
    __shared__ int s_carry;
    int t = threadIdx.x;
    if (t == 0) s_carry = 0;
    __syncthreads();
    for (int base = 0; base < n; base += 1024) {
        int idx = base + t;
        int v = (idx < n) ? deg[idx] : 0;
        tmp[t] = v;
        __syncthreads();
        for (int off = 1; off < 1024; off <<= 1) {
            int x = (t >= off) ? tmp[t - off] : 0;
            __syncthreads();
            tmp[t] += x;
            __syncthreads();
        }
        int excl = tmp[t] - v + s_carry;
        if (idx < n) cur[idx] = excl;
        __syncthreads();
        if (t == 0) s_carry += tmp[1023];
        __syncthreads();
    }
}
__global__ void bin_kernel(const int* __restrict__ seg1, const int* __restrict__ seg2,
                           int* cur1, int* cur2,
                           int* __restrict__ el1, int* __restrict__ el2, int E) {
    int e = blockIdx.x * blockDim.x + threadIdx.x;
    if (e >= E) return;
    int p1 = atomicAdd(&cur1[seg1[e]], 1);
    el1[p1] = e;
    int p2 = atomicAdd(&cur2[seg2[e]], 1);
    el2[p2] = e;
}
__global__ void gather_out_kernel(int N, const int* __restrict__ cur, const int* __restrict__ deg,
                                  const int* __restrict__ el, const float* __restrict__ trans,
                                  const int* __restrict__ segOther, const float* __restrict__ Vother,
                                  float* __restrict__ e_out, float* __restrict__ msg_out,
                                  const float* __restrict__ Wo, const float* __restrict__ bo,
                                  float invT) {
    __shared__ float sW[64 * 64];
    int tid = threadIdx.x;
    for (int i = tid; i < 4096; i += blockDim.x) sW[i] = Wo[i];
    __syncthreads();
    int wave = tid >> 6, lane = tid & 63;
    int wpb = blockDim.x >> 6;
    int node = blockIdx.x * wpb + wave;
    if (node >= N) return;
    int d = deg[node];
    int start = cur[node] - d;
    float acc = 0.f;
    if (d > 0) {
        float m = -INFINITY;
        for (int k = lane; k < d; k += 64) m = fmaxf(m, trans[el[start + k]]);
        m = fmaxf(m, __shfl_xor(m, 1));
        m = fmaxf(m, __shfl_xor(m, 2));
        m = fmaxf(m, __shfl_xor(m, 4));
        m = fmaxf(m, __shfl_xor(m, 8));
        m = fmaxf(m, __shfl_xor(m, 16));
        m = fmaxf(m, __shfl_xor(m, 32));
        float s = 0.f;
        for (int k = lane; k < d; k += 64) s += __expf((trans[el[start + k]] - m) * invT);
        s += __shfl_xor(s, 1);
        s += __shfl_xor(s, 2);
        s += __shfl_xor(s, 4);
        s += __shfl_xor(s, 8);
        s += __shfl_xor(s, 16);
        s += __shfl_xor(s, 32);
        float inv = 1.f / (s + 1e-8f);
        for (int base = 0; base < d; base += 64) {
            int k = base + lane;
            float w = 0.f;
            int j = 0;
            if (k < d) {
                int e = el[start + k];
                w = __expf((trans[e] - m) * invT) * inv;
                e_out[e] = w;
                j = segOther[e];
            }
            int cnt = (d - base < 64) ? (d - base) : 64;
            for (int q = 0; q < cnt; ++q) {
                float wq = __shfl(w, q);
                int jq = __shfl(j, q);
                acc = fmaf(wq, Vother[(long)jq * 64 + lane], acc);
            }
        }
    }
    float o = bo[lane];
#pragma unroll
    for (int k = 0; k < 64; ++k) {
        float xv = __shfl(acc, k);
        o = fmaf(xv, sW[k * 64 + lane], o);
    }
    o = (o >= 0.f) ? o : 0.01f * o;
    msg_out[(long)node * 64 + lane] = o;
}

extern "C" void kernel_launch(void* const* d_in, const int* in_sizes, int n_in,
                              void* d_out, int out_size, void* d_ws, size_t ws_size,
                              hipStream_t stream) {
    const float* node1 = (const float*)d_in[0];
    const int* seg1 = (const int*)d_in[1];
    const float* node2 = (const float*)d_in[3];
    const int* seg2 = (const int*)d_in[4];
    const float* Wk = (const float*)d_in[6];
    const float* Wv = (const float*)d_in[7];
    const float* Wo = (const float*)d_in[8];
    const float* bo = (const float*)d_in[9];

    int n1 = in_sizes[0] / 64;
    int n2 = in_sizes[3] / 64;
    int E = in_sizes[1];

    float* out = (float*)d_out;
    float* msg1 = out;
    float* msg2 = msg1 + (long)n1 * 64;
    float* e1 = msg2 + (long)n2 * 64;
    float* e2 = e1 + E;

    const float invT = 1.0f / sqrtf(64.0f);
    int nb1 = (n1 + BSZ - 1) >> BSH;
    int nb2 = (n2 + BSZ - 1) >> BSH;
    long Epad = (E + 1) & ~1L;

    // ---- fast-path layout (8B-aligned prefix for float2 arrays) ----
    float* ws = (float*)d_ws;
    float2* csr1 = (float2*)ws;                         // 2E words
    float2* csr2 = csr1 + E;                            // 2E words
    float* V1 = (float*)(csr2 + E);                     // n1*64
    float* V2 = V1 + (long)n1 * 64;                     // n2*64
    float* trans = V2 + (long)n2 * 64;                  // Epad
    float2* minv1 = (float2*)(trans + Epad);            // 2*n1 words
    float2* minv2 = minv1 + n1;                         // 2*n2 words
    float* K1 = (float*)(minv2 + n2);                   // n1*64 (tmp1 alias)
    float* K2 = K1 + (long)n1 * 64;                     // n2*64 (tmp2 alias)
    int* deg1 = (int*)(K2 + (long)n2 * 64);             // n1
    int* deg2 = deg1 + n1;                              // n2
    int* cur1 = deg2 + n2;                              // n1
    int* cur2 = cur1 + n1;                              // n2
    int* bb1 = cur2 + n2;                               // nb1+1
    int* bb2 = bb1 + nb1 + 1;                           // nb2+1
    int* bcur1 = bb2 + nb2 + 1;                         // nb1
    int* bcur2 = bcur1 + nb1;                           // nb2
    int* bcnt1 = bcur2 + nb2;                           // nb1
    int* bcnt2 = bcnt1 + nb1;                           // nb2
    long fp_words = 4L * E + 2L * ((long)n1 * 64 + (long)n2 * 64) + Epad
                  + 2L * (n1 + n2) + 2L * (n1 + n2)
                  + 3L * (nb1 + nb2) + 2;
    bool fast = (E <= (1 << 20)) && (nb1 <= MAXNB) && (nb2 <= MAXNB)
             && ((long)E <= (long)n1 * 64) && ((long)E <= (long)n2 * 64)
             && ((size_t)fp_words * 4 <= ws_size);

    if (fast) {
        proj_kernel<<<(n1 + 3) / 4, 256, 0, stream>>>(node1, n1, Wk, Wv, K1, V1);
        proj_kernel<<<(n2 + 3) / 4, 256, 0, stream>>>(node2, n2, Wk, Wv, K2, V2);
        {
            long threads = (long)E * 16;
            int blocks = (int)((threads + 255) / 256);
            logit_kernel<<<blocks, 256, 0, stream>>>(K1, K2, seg1, seg2, trans, E);
        }
        unsigned* tmp1 = (unsigned*)K1;  // K dead after logit
        unsigned* tmp2 = (unsigned*)K2;

        zero_small_kernel<<<1, 256, 0, stream>>>(bcnt1, bcnt2, nb1, nb2);
        bucket_count_kernel<<<512, 256, 0, stream>>>(seg1, seg2, E, bcnt1, bcnt2, nb1, nb2);
        bucket_scan_kernel<<<1, MAXNB, 0, stream>>>(bcnt1, bcnt2, bb1, bb2, bcur1, bcur2,
                                                    nb1, nb2, E);
        partition_kernel<<<(E + PT_TILE - 1) / PT_TILE, 256, 0, stream>>>(
            seg1, seg2, E, bcur1, bcur2, tmp1, tmp2);
        bin2_kernel<<<nb1, 256, 0, stream>>>(tmp1, bb1, n1, cur1, deg1, csr1, trans, seg2);
        bin2_kernel<<<nb2, 256, 0, stream>>>(tmp2, bb2, n2, cur2, deg2, csr2, trans, seg1);

        gather_ms_kernel<<<(n1 + 3) / 4, 256, 0, stream>>>(
            n1, cur1, deg1, csr1, V2, minv1, msg1, Wo, bo, invT);
        gather_ms_kernel<<<(n2 + 3) / 4, 256, 0, stream>>>(
            n2, cur2, deg2, csr2, V1, minv2, msg2, Wo, bo, invT);

        edge_w_kernel<<<(E + 255) / 256, 256, 0, stream>>>(
            trans, seg1, seg2, minv1, minv2, e1, e2, E, invT);
    } else {
        // fallback: R2-proven path
        float* K1f = ws;
        float* V1f = K1f + (long)n1 * 64;
        float* K2f = V1f + (long)n1 * 64;
        float* V2f = K2f + (long)n2 * 64;
        float* transf = V2f + (long)n2 * 64;
        int* deg1f = (int*)(transf + E);
        int* deg2f = deg1f + n1;
        int* cur1f = deg2f + n2;
        int* cur2f = cur1f + n1;
        int* el1 = (int*)K1f;
        int* el2 = (int*)K2f;
        int nmax = n1 > n2 ? n1 : n2;

        proj_kernel<<<(n1 + 3) / 4, 256, 0, stream>>>(node1, n1, Wk, Wv, K1f, V1f);
        proj_kernel<<<(n2 + 3) / 4, 256, 0, stream>>>(node2, n2, Wk, Wv, K2f, V2f);
        {
            long threads = (long)E * 16;
            int blocks = (int)((threads + 255) / 256);
            logit_kernel<<<blocks, 256, 0, stream>>>(K1f, K2f, seg1, seg2, transf, E);
        }
        zero_deg_kernel<<<(nmax + 255) / 256, 256, 0, stream>>>(deg1f, deg2f, n1, n2);
        hist_kernel<<<(E + 255) / 256, 256, 0, stream>>>(seg1, seg2, deg1f, deg2f, E);
        scan2_kernel<<<2, 1024, 0, stream>>>(deg1f, cur1f, n1, deg2f, cur2f, n2);
        bin_kernel<<<(E + 255) / 256, 256, 0, stream>>>(seg1, seg2, cur1f, cur2f, el1, el2, E);

        gather_out_kernel<<<(n1 + 3) / 4, 256, 0, stream>>>(
            n1, cur1f, deg1f, el1, transf, seg2, V2f, e1, msg1, Wo, bo, invT);
        gather_out_kernel<<<(n2 + 3) / 4, 256, 0, stream>>>(
            n2, cur2f, deg2f, el2, transf, seg1, V1f, e2, msg2, Wo, bo, invT);
    }
}

// Round 5
// 267.355 us; speedup vs baseline: 7.6501x; 1.4877x over previous
//
#include <hip/hip_runtime.h>
#include <math.h>

#define BSH 7              // 128 nodes per bucket
#define BSZ (1 << BSH)
#define MAXNB 256          // max buckets per side
#define PT_TILE 4096       // edges per partition block

__device__ __forceinline__ float readlane_f(float v, int l) {
    return __uint_as_float((unsigned)__builtin_amdgcn_readlane((int)__float_as_uint(v), l));
}

// ---------- fused projections: K = X@Wk, V = X@Wv (both sides, one launch) ----------
__global__ void proj_kernel(const float* __restrict__ X1, int n1, int g1,
                            const float* __restrict__ X2, int n2,
                            const float* __restrict__ Wk,
                            const float* __restrict__ Wv,
                            float* __restrict__ K1, float* __restrict__ V1,
                            float* __restrict__ K2, float* __restrict__ V2) {
    __shared__ float sWk[64 * 64];
    __shared__ float sWv[64 * 64];
    int tid = threadIdx.x;
    for (int i = tid; i < 4096; i += blockDim.x) { sWk[i] = Wk[i]; sWv[i] = Wv[i]; }
    __syncthreads();
    int wave = tid >> 6, lane = tid & 63;
    const float* X; float* K; float* V; int N, nd0;
    if ((int)blockIdx.x < g1) { X = X1; K = K1; V = V1; N = n1; nd0 = blockIdx.x * 4; }
    else { X = X2; K = K2; V = V2; N = n2; nd0 = (blockIdx.x - g1) * 4; }
    int n = nd0 + wave;
    if (n >= N) return;
    float x = X[(long)n * 64 + lane];
    float ak = 0.f, av = 0.f;
#pragma unroll
    for (int k = 0; k < 64; ++k) {
        float xv = __shfl(x, k);
        ak = fmaf(xv, sWk[k * 64 + lane], ak);
        av = fmaf(xv, sWv[k * 64 + lane], av);
    }
    K[(long)n * 64 + lane] = ak;
    V[(long)n * 64 + lane] = av;
}

// ---------- edge logits ----------
__global__ void logit_kernel(const float* __restrict__ K1, const float* __restrict__ K2,
                             const int* __restrict__ seg1, const int* __restrict__ seg2,
                             float* __restrict__ trans, int E) {
    int tid = blockIdx.x * blockDim.x + threadIdx.x;
    int e = tid >> 4, g = tid & 15;
    if (e >= E) return;
    int i1 = seg1[e], i2 = seg2[e];
    float4 a = ((const float4*)(K1 + (long)i1 * 64))[g];
    float4 b = ((const float4*)(K2 + (long)i2 * 64))[g];
    float d = a.x * b.x + a.y * b.y + a.z * b.z + a.w * b.w;
    d += __shfl_xor(d, 1);
    d += __shfl_xor(d, 2);
    d += __shfl_xor(d, 4);
    d += __shfl_xor(d, 8);
    if (g == 0) trans[e] = d;
}

// ---------- bucket histogram ----------
__global__ void zero_small_kernel(int* b1, int* b2, int nb1, int nb2) {
    int i = threadIdx.x;
    if (i < nb1) b1[i] = 0;
    if (i < nb2) b2[i] = 0;
}

__global__ void bucket_count_kernel(const int* __restrict__ seg1, const int* __restrict__ seg2,
                                    int E, int* bcnt1, int* bcnt2, int nb1, int nb2) {
    __shared__ int c1[MAXNB], c2[MAXNB];
    int tid = threadIdx.x;
    for (int i = tid; i < MAXNB; i += blockDim.x) { c1[i] = 0; c2[i] = 0; }
    __syncthreads();
    for (int i = blockIdx.x * blockDim.x + tid; i < E; i += gridDim.x * blockDim.x) {
        atomicAdd(&c1[seg1[i] >> BSH], 1);
        atomicAdd(&c2[seg2[i] >> BSH], 1);
    }
    __syncthreads();
    for (int i = tid; i < nb1; i += blockDim.x) if (c1[i]) atomicAdd(&bcnt1[i], c1[i]);
    for (int i = tid; i < nb2; i += blockDim.x) if (c2[i]) atomicAdd(&bcnt2[i], c2[i]);
}

// ---------- scan bucket counts ----------
__global__ void bucket_scan_kernel(const int* __restrict__ bcnt1, const int* __restrict__ bcnt2,
                                   int* bb1, int* bb2, int* bcur1, int* bcur2,
                                   int nb1, int nb2, int E) {
    __shared__ int tmp[MAXNB];
    int t = threadIdx.x;
    int v1 = (t < nb1) ? bcnt1[t] : 0;
    tmp[t] = v1;
    __syncthreads();
    for (int off = 1; off < MAXNB; off <<= 1) {
        int x = (t >= off) ? tmp[t - off] : 0;
        __syncthreads();
        tmp[t] += x;
        __syncthreads();
    }
    if (t < nb1) { int excl = tmp[t] - v1; bb1[t] = excl; bcur1[t] = excl; }
    if (t == 0) bb1[nb1] = E;
    __syncthreads();
    int v2 = (t < nb2) ? bcnt2[t] : 0;
    tmp[t] = v2;
    __syncthreads();
    for (int off = 1; off < MAXNB; off <<= 1) {
        int x = (t >= off) ? tmp[t - off] : 0;
        __syncthreads();
        tmp[t] += x;
        __syncthreads();
    }
    if (t < nb2) { int excl = tmp[t] - v2; bb2[t] = excl; bcur2[t] = excl; }
    if (t == 0) bb2[nb2] = E;
}

// ---------- partition: emit (t, nodelocal<<25|j) records into bucket regions ----------
__global__ void partition_kernel(const int* __restrict__ seg1, const int* __restrict__ seg2,
                                 const float* __restrict__ trans, int E,
                                 int* bcur1, int* bcur2,
                                 float2* __restrict__ tmp1, float2* __restrict__ tmp2) {
    __shared__ int c1[MAXNB], c2[MAXNB];
    int tid = threadIdx.x;
    int base = blockIdx.x * PT_TILE;
    int end = base + PT_TILE;
    if (end > E) end = E;
    for (int i = tid; i < MAXNB; i += blockDim.x) { c1[i] = 0; c2[i] = 0; }
    __syncthreads();
    for (int i = base + tid; i < end; i += blockDim.x) {
        atomicAdd(&c1[seg1[i] >> BSH], 1);
        atomicAdd(&c2[seg2[i] >> BSH], 1);
    }
    __syncthreads();
    for (int i = tid; i < MAXNB; i += blockDim.x) {
        int n = c1[i]; c1[i] = n ? atomicAdd(&bcur1[i], n) : 0;
        n = c2[i];     c2[i] = n ? atomicAdd(&bcur2[i], n) : 0;
    }
    __syncthreads();
    for (int i = base + tid; i < end; i += blockDim.x) {
        int s1 = seg1[i], s2 = seg2[i];
        float t = trans[i];
        int p = atomicAdd(&c1[s1 >> BSH], 1);
        tmp1[p] = make_float2(t, __int_as_float(((s1 & (BSZ - 1)) << 25) | s2));
        int q = atomicAdd(&c2[s2 >> BSH], 1);
        tmp2[q] = make_float2(t, __int_as_float(((s2 & (BSZ - 1)) << 25) | s1));
    }
}

// ---------- bin2 (fused both sides): bucket records -> node-sorted CSR (t, j) ----------
__global__ void bin2_kernel(const float2* __restrict__ tmp1, const int* __restrict__ bb1,
                            int n1, int* __restrict__ cur1, int* __restrict__ deg1,
                            float2* __restrict__ csr1,
                            const float2* __restrict__ tmp2, const int* __restrict__ bb2,
                            int n2, int* __restrict__ cur2, int* __restrict__ deg2,
                            float2* __restrict__ csr2, int nb1) {
    __shared__ int cnt[BSZ];
    __shared__ int off[BSZ];
    __shared__ int sc[BSZ];
    int b = blockIdx.x;
    const float2* tmp; const int* bb; int n; int* cur; int* deg; float2* csr;
    if (b < nb1) { tmp = tmp1; bb = bb1; n = n1; cur = cur1; deg = deg1; csr = csr1; }
    else { b -= nb1; tmp = tmp2; bb = bb2; n = n2; cur = cur2; deg = deg2; csr = csr2; }
    int tid = threadIdx.x;
    int node0 = b << BSH;
    int s = bb[b], e_end = bb[b + 1];
    for (int i = tid; i < BSZ; i += blockDim.x) cnt[i] = 0;
    __syncthreads();
    for (int i = s + tid; i < e_end; i += blockDim.x)
        atomicAdd(&cnt[((unsigned)__float_as_int(tmp[i].y)) >> 25], 1);
    __syncthreads();
    if (tid < BSZ) sc[tid] = cnt[tid];
    __syncthreads();
    for (int o = 1; o < BSZ; o <<= 1) {
        int x = (tid >= o && tid < BSZ) ? sc[tid - o] : 0;
        __syncthreads();
        if (tid < BSZ) sc[tid] += x;
        __syncthreads();
    }
    if (tid < BSZ) {
        int excl = sc[tid] - cnt[tid] + s;
        off[tid] = excl;
        int node = node0 + tid;
        if (node < n) { cur[node] = excl; deg[node] = cnt[tid]; }
    }
    __syncthreads();
    for (int i = s + tid; i < e_end; i += blockDim.x) {
        float2 r = tmp[i];
        unsigned pay = (unsigned)__float_as_int(r.y);
        int pos = atomicAdd(&off[pay >> 25], 1);
        csr[pos] = make_float2(r.x, __int_as_float((int)(pay & 0x1FFFFFFu)));
    }
}

// ---------- gather (fused both sides): softmax + 4-edge-in-flight V gather + Wo ----------
__global__ void gather_ms_kernel(int n1, int n2, int g1,
                                 const int* __restrict__ cur1, const int* __restrict__ deg1,
                                 const float2* __restrict__ csr1, const float* __restrict__ Vb2,
                                 float2* __restrict__ minv1, float* __restrict__ msg1,
                                 const int* __restrict__ cur2, const int* __restrict__ deg2,
                                 const float2* __restrict__ csr2, const float* __restrict__ Vb1,
                                 float2* __restrict__ minv2, float* __restrict__ msg2,
                                 const float* __restrict__ Wo, const float* __restrict__ bo,
                                 float invT) {
    __shared__ float sW[64 * 64];
    int tid = threadIdx.x;
    for (int i = tid; i < 4096; i += blockDim.x) sW[i] = Wo[i];
    __syncthreads();
    int wave = tid >> 6, lane = tid & 63;
    const int *cur, *deg; const float2* csr; const float* V; float2* minv; float* msg;
    int N, nd0;
    if ((int)blockIdx.x < g1) {
        cur = cur1; deg = deg1; csr = csr1; V = Vb2; minv = minv1; msg = msg1;
        N = n1; nd0 = blockIdx.x * 4;
    } else {
        cur = cur2; deg = deg2; csr = csr2; V = Vb1; minv = minv2; msg = msg2;
        N = n2; nd0 = (blockIdx.x - g1) * 4;
    }
    int nd = nd0 + wave;
    if (nd >= N) return;
    int d = deg[nd];
    int start = cur[nd];
    int g = lane >> 4, l = lane & 15;
    float4 acc = make_float4(0.f, 0.f, 0.f, 0.f);
    if (d > 0) {
        float t0 = -INFINITY, t1 = -INFINITY, t2 = -INFINITY;
        int j0 = 0, j1 = 0, j2 = 0;
        if (lane < d)       { float2 r = csr[start + lane];       t0 = r.x; j0 = __float_as_int(r.y); }
        if (lane + 64 < d)  { float2 r = csr[start + lane + 64];  t1 = r.x; j1 = __float_as_int(r.y); }
        if (lane + 128 < d) { float2 r = csr[start + lane + 128]; t2 = r.x; j2 = __float_as_int(r.y); }
        float m = fmaxf(fmaxf(t0, t1), t2);
        for (int k = 192 + lane; k < d; k += 64) m = fmaxf(m, csr[start + k].x);
        m = fmaxf(m, __shfl_xor(m, 1));
        m = fmaxf(m, __shfl_xor(m, 2));
        m = fmaxf(m, __shfl_xor(m, 4));
        m = fmaxf(m, __shfl_xor(m, 8));
        m = fmaxf(m, __shfl_xor(m, 16));
        m = fmaxf(m, __shfl_xor(m, 32));
        float p0 = (lane < d)       ? __expf((t0 - m) * invT) : 0.f;
        float p1 = (lane + 64 < d)  ? __expf((t1 - m) * invT) : 0.f;
        float p2 = (lane + 128 < d) ? __expf((t2 - m) * invT) : 0.f;
        float s = p0 + p1 + p2;
        for (int k = 192 + lane; k < d; k += 64) s += __expf((csr[start + k].x - m) * invT);
        s += __shfl_xor(s, 1);
        s += __shfl_xor(s, 2);
        s += __shfl_xor(s, 4);
        s += __shfl_xor(s, 8);
        s += __shfl_xor(s, 16);
        s += __shfl_xor(s, 32);
        float inv = 1.f / (s + 1e-8f);
        if (lane == 0) minv[nd] = make_float2(m, inv);
        float w0 = p0 * inv, w1 = p1 * inv, w2 = p2 * inv;
        // 4 edges in flight: group g handles edge k+g; 16 lanes x float4 per row
        int c0 = d < 64 ? d : 64;
#pragma unroll 4
        for (int k = 0; k < c0; k += 4) {
            float w = __shfl(w0, k + g);
            int j = __shfl(j0, k + g);
            float4 v = *(const float4*)(V + (long)j * 64 + l * 4);
            acc.x = fmaf(w, v.x, acc.x);
            acc.y = fmaf(w, v.y, acc.y);
            acc.z = fmaf(w, v.z, acc.z);
            acc.w = fmaf(w, v.w, acc.w);
        }
        if (d > 64) {
            int c1 = (d - 64) < 64 ? (d - 64) : 64;
#pragma unroll 4
            for (int k = 0; k < c1; k += 4) {
                float w = __shfl(w1, k + g);
                int j = __shfl(j1, k + g);
                float4 v = *(const float4*)(V + (long)j * 64 + l * 4);
                acc.x = fmaf(w, v.x, acc.x);
                acc.y = fmaf(w, v.y, acc.y);
                acc.z = fmaf(w, v.z, acc.z);
                acc.w = fmaf(w, v.w, acc.w);
            }
        }
        if (d > 128) {
            int c2 = (d - 128) < 64 ? (d - 128) : 64;
#pragma unroll 4
            for (int k = 0; k < c2; k += 4) {
                float w = __shfl(w2, k + g);
                int j = __shfl(j2, k + g);
                float4 v = *(const float4*)(V + (long)j * 64 + l * 4);
                acc.x = fmaf(w, v.x, acc.x);
                acc.y = fmaf(w, v.y, acc.y);
                acc.z = fmaf(w, v.z, acc.z);
                acc.w = fmaf(w, v.w, acc.w);
            }
        }
        for (int base = 192; base < d; base += 64) {
            int k = base + lane;
            float wr = 0.f; int jr = 0;
            if (k < d) {
                float2 r = csr[start + k];
                wr = __expf((r.x - m) * invT) * inv;
                jr = __float_as_int(r.y);
            }
            int cc = (d - base) < 64 ? (d - base) : 64;
            for (int k2 = 0; k2 < cc; k2 += 4) {
                float w = __shfl(wr, k2 + g);
                int j = __shfl(jr, k2 + g);
                float4 v = *(const float4*)(V + (long)j * 64 + l * 4);
                acc.x = fmaf(w, v.x, acc.x);
                acc.y = fmaf(w, v.y, acc.y);
                acc.z = fmaf(w, v.z, acc.z);
                acc.w = fmaf(w, v.w, acc.w);
            }
        }
        // reduce partial sums across the 4 groups (lanes l, l+16, l+32, l+48)
        acc.x += __shfl_xor(acc.x, 16); acc.y += __shfl_xor(acc.y, 16);
        acc.z += __shfl_xor(acc.z, 16); acc.w += __shfl_xor(acc.w, 16);
        acc.x += __shfl_xor(acc.x, 32); acc.y += __shfl_xor(acc.y, 32);
        acc.z += __shfl_xor(acc.z, 32); acc.w += __shfl_xor(acc.w, 32);
    }
    // fused Wo GEMM + bias + leaky relu; lane kk (<16) holds components 4kk..4kk+3
    float o = bo[lane];
#pragma unroll
    for (int kk = 0; kk < 16; ++kk) {
        float a0 = readlane_f(acc.x, kk);
        float a1 = readlane_f(acc.y, kk);
        float a2 = readlane_f(acc.z, kk);
        float a3 = readlane_f(acc.w, kk);
        o = fmaf(a0, sW[(4 * kk + 0) * 64 + lane], o);
        o = fmaf(a1, sW[(4 * kk + 1) * 64 + lane], o);
        o = fmaf(a2, sW[(4 * kk + 2) * 64 + lane], o);
        o = fmaf(a3, sW[(4 * kk + 3) * 64 + lane], o);
    }
    o = (o >= 0.f) ? o : 0.01f * o;
    msg[(long)nd * 64 + lane] = o;
}

// ---------- coalesced edge weights ----------
__global__ void edge_w_kernel(const float* __restrict__ trans,
                              const int* __restrict__ seg1, const int* __restrict__ seg2,
                              const float2* __restrict__ minv1, const float2* __restrict__ minv2,
                              float* __restrict__ e1, float* __restrict__ e2,
                              int E, float invT) {
    int e = blockIdx.x * blockDim.x + threadIdx.x;
    if (e >= E) return;
    float t = trans[e];
    float2 a = minv1[seg1[e]];
    float2 b = minv2[seg2[e]];
    e1[e] = __expf((t - a.x) * invT) * a.y;
    e2[e] = __expf((t - b.x) * invT) * b.y;
}

// ---------- fallback path kernels (R2-proven) ----------
__global__ void proj1_kernel(const float* __restrict__ X, int N,
                             const float* __restrict__ Wk,
                             const float* __restrict__ Wv,
                             float* __restrict__ K, float* __restrict__ V) {
    __shared__ float sWk[64 * 64];
    __shared__ float sWv[64 * 64];
    int tid = threadIdx.x;
    for (int i = tid; i < 4096; i += blockDim.x) { sWk[i] = Wk[i]; sWv[i] = Wv[i]; }
    __syncthreads();
    int wave = tid >> 6, lane = tid & 63;
    int wpb = blockDim.x >> 6;
    for (int n = blockIdx.x * wpb + wave; n < N; n += gridDim.x * wpb) {
        float x = X[n * 64 + lane];
        float ak = 0.f, av = 0.f;
#pragma unroll
        for (int k = 0; k < 64; ++k) {
            float xv = __shfl(x, k);
            ak = fmaf(xv, sWk[k * 64 + lane], ak);
            av = fmaf(xv, sWv[k * 64 + lane], av);
        }
        K[n * 64 + lane] = ak;
        V[n * 64 + lane] = av;
    }
}
__global__ void zero_deg_kernel(int* d1, int* d2, int n1, int n2) {
    int i = blockIdx.x * blockDim.x + threadIdx.x;
    if (i < n1) d1[i] = 0;
    if (i < n2) d2[i] = 0;
}
__global__ void hist_kernel(const int* __restrict__ seg1, const int* __restrict__ seg2,
                            int* deg1, int* deg2, int E) {
    int e = blockIdx.x * blockDim.x + threadIdx.x;
    if (e >= E) return;
    atomicAdd(&deg1[seg1[e]], 1);
    atomicAdd(&deg2[seg2[e]], 1);
}
__global__ void scan2_kernel(const int* __restrict__ d1, int* __restrict__ c1, int n1,
                             const int* __restrict__ d2, int* __restrict__ c2, int n2) {
    const int* deg = blockIdx.x ? d2 : d1;
    int* cur = blockIdx.x ? c2 : c1;
    int n = blockIdx.x ? n2 : n1;
    __shared__ int tmp[1024];
    __shared__ int s_carry;
    int t = threadIdx.x;
    if (t == 0) s_carry = 0;
    __syncthreads();
    for (int base = 0; base < n; base += 1024) {
        int idx = base + t;
        int v = (idx < n) ? deg[idx] : 0;
        tmp[t] = v;
        __syncthreads();
        for (int off = 1; off < 1024; off <<= 1) {
            int x = (t >= off) ? tmp[t - off] : 0;
            __syncthreads();
            tmp[t] += x;
            __syncthreads();
        }
        int excl = tmp[t] - v + s_carry;
        if (idx < n) cur[idx] = excl;
        __syncthreads();
        if (t == 0) s_carry += tmp[1023];
        __syncthreads();
    }
}
__global__ void bin_kernel(const int* __restrict__ seg1, const int* __restrict__ seg2,
                           int* cur1, int* cur2,
                           int* __restrict__ el1, int* __restrict__ el2, int E) {
    int e = blockIdx.x * blockDim.x + threadIdx.x;
    if (e >= E) return;
    int p1 = atomicAdd(&cur1[seg1[e]], 1);
    el1[p1] = e;
    int p2 = atomicAdd(&cur2[seg2[e]], 1);
    el2[p2] = e;
}
__global__ void gather_out_kernel(int N, const int* __restrict__ cur, const int* __restrict__ deg,
                                  const int* __restrict__ el, const float* __restrict__ trans,
                                  const int* __restrict__ segOther, const float* __restrict__ Vother,
                                  float* __restrict__ e_out, float* __restrict__ msg_out,
                                  const float* __restrict__ Wo, const float* __restrict__ bo,
                                  float invT) {
    __shared__ float sW[64 * 64];
    int tid = threadIdx.x;
    for (int i = tid; i < 4096; i += blockDim.x) sW[i] = Wo[i];
    __syncthreads();
    int wave = tid >> 6, lane = tid & 63;
    int wpb = blockDim.x >> 6;
    int node = blockIdx.x * wpb + wave;
    if (node >= N) return;
    int d = deg[node];
    int start = cur[node] - d;
    float acc = 0.f;
    if (d > 0) {
        float m = -INFINITY;
        for (int k = lane; k < d; k += 64) m = fmaxf(m, trans[el[start + k]]);
        m = fmaxf(m, __shfl_xor(m, 1));
        m = fmaxf(m, __shfl_xor(m, 2));
        m = fmaxf(m, __shfl_xor(m, 4));
        m = fmaxf(m, __shfl_xor(m, 8));
        m = fmaxf(m, __shfl_xor(m, 16));
        m = fmaxf(m, __shfl_xor(m, 32));
        float s = 0.f;
        for (int k = lane; k < d; k += 64) s += __expf((trans[el[start + k]] - m) * invT);
        s += __shfl_xor(s, 1);
        s += __shfl_xor(s, 2);
        s += __shfl_xor(s, 4);
        s += __shfl_xor(s, 8);
        s += __shfl_xor(s, 16);
        s += __shfl_xor(s, 32);
        float inv = 1.f / (s + 1e-8f);
        for (int base = 0; base < d; base += 64) {
            int k = base + lane;
            float w = 0.f;
            int j = 0;
            if (k < d) {
                int e = el[start + k];
                w = __expf((trans[e] - m) * invT) * inv;
                e_out[e] = w;
                j = segOther[e];
            }
            int cnt = (d - base < 64) ? (d - base) : 64;
            for (int q = 0; q < cnt; ++q) {
                float wq = __shfl(w, q);
                int jq = __shfl(j, q);
                acc = fmaf(wq, Vother[(long)jq * 64 + lane], acc);
            }
        }
    }
    float o = bo[lane];
#pragma unroll
    for (int k = 0; k < 64; ++k) {
        float xv = __shfl(acc, k);
        o = fmaf(xv, sW[k * 64 + lane], o);
    }
    o = (o >= 0.f) ? o : 0.01f * o;
    msg_out[(long)node * 64 + lane] = o;
}

extern "C" void kernel_launch(void* const* d_in, const int* in_sizes, int n_in,
                              void* d_out, int out_size, void* d_ws, size_t ws_size,
                              hipStream_t stream) {
    const float* node1 = (const float*)d_in[0];
    const int* seg1 = (const int*)d_in[1];
    const float* node2 = (const float*)d_in[3];
    const int* seg2 = (const int*)d_in[4];
    const float* Wk = (const float*)d_in[6];
    const float* Wv = (const float*)d_in[7];
    const float* Wo = (const float*)d_in[8];
    const float* bo = (const float*)d_in[9];

    int n1 = in_sizes[0] / 64;
    int n2 = in_sizes[3] / 64;
    int E = in_sizes[1];

    float* out = (float*)d_out;
    float* msg1 = out;
    float* msg2 = msg1 + (long)n1 * 64;
    float* e1 = msg2 + (long)n2 * 64;
    float* e2 = e1 + E;

    const float invT = 1.0f / sqrtf(64.0f);
    int nb1 = (n1 + BSZ - 1) >> BSH;
    int nb2 = (n2 + BSZ - 1) >> BSH;
    long Epad = (E + 1) & ~1L;

    // ---- fast-path layout (8B alignment maintained for float2 arrays) ----
    float* ws = (float*)d_ws;
    float2* csr1 = (float2*)ws;                         // E records
    float2* csr2 = csr1 + E;                            // E
    float2* tmp1 = csr2 + E;                            // E
    float2* tmp2 = tmp1 + E;                            // E
    float* V1 = (float*)(tmp2 + E);                     // n1*64
    float* V2 = V1 + (long)n1 * 64;                     // n2*64
    float* trans = V2 + (long)n2 * 64;                  // Epad
    float2* minv1 = (float2*)(trans + Epad);            // n1
    float2* minv2 = minv1 + n1;                         // n2
    float* K1 = (float*)(minv2 + n2);                   // n1*64
    float* K2 = K1 + (long)n1 * 64;                     // n2*64
    int* deg1 = (int*)(K2 + (long)n2 * 64);             // n1
    int* deg2 = deg1 + n1;                              // n2
    int* cur1 = deg2 + n2;                              // n1
    int* cur2 = cur1 + n1;                              // n2
    int* bb1 = cur2 + n2;                               // nb1+1
    int* bb2 = bb1 + nb1 + 1;                           // nb2+1
    int* bcur1 = bb2 + nb2 + 1;                         // nb1
    int* bcur2 = bcur1 + nb1;                           // nb2
    int* bcnt1 = bcur2 + nb2;                           // nb1
    int* bcnt2 = bcnt1 + nb1;                           // nb2
    long fp_words = 8L * E + 2L * 64 * ((long)n1 + n2) + Epad
                  + 4L * (n1 + n2) + 3L * (nb1 + nb2) + 2;
    bool fast = (E <= (1 << 20)) && (nb1 <= MAXNB) && (nb2 <= MAXNB)
             && (n1 < (1 << 25)) && (n2 < (1 << 25))
             && ((size_t)fp_words * 4 <= ws_size);

    if (fast) {
        int g1p = (n1 + 3) / 4, g2p = (n2 + 3) / 4;
        proj_kernel<<<g1p + g2p, 256, 0, stream>>>(node1, n1, g1p, node2, n2,
                                                   Wk, Wv, K1, V1, K2, V2);
        {
            long threads = (long)E * 16;
            int blocks = (int)((threads + 255) / 256);
            logit_kernel<<<blocks, 256, 0, stream>>>(K1, K2, seg1, seg2, trans, E);
        }
        zero_small_kernel<<<1, 256, 0, stream>>>(bcnt1, bcnt2, nb1, nb2);
        bucket_count_kernel<<<512, 256, 0, stream>>>(seg1, seg2, E, bcnt1, bcnt2, nb1, nb2);
        bucket_scan_kernel<<<1, MAXNB, 0, stream>>>(bcnt1, bcnt2, bb1, bb2, bcur1, bcur2,
                                                    nb1, nb2, E);
        partition_kernel<<<(E + PT_TILE - 1) / PT_TILE, 256, 0, stream>>>(
            seg1, seg2, trans, E, bcur1, bcur2, tmp1, tmp2);
        bin2_kernel<<<nb1 + nb2, 256, 0, stream>>>(tmp1, bb1, n1, cur1, deg1, csr1,
                                                   tmp2, bb2, n2, cur2, deg2, csr2, nb1);
        gather_ms_kernel<<<g1p + g2p, 256, 0, stream>>>(
            n1, n2, g1p, cur1, deg1, csr1, V2, minv1, msg1,
            cur2, deg2, csr2, V1, minv2, msg2, Wo, bo, invT);
        edge_w_kernel<<<(E + 255) / 256, 256, 0, stream>>>(
            trans, seg1, seg2, minv1, minv2, e1, e2, E, invT);
    } else {
        // fallback: R2-proven path
        float* K1f = ws;
        float* V1f = K1f + (long)n1 * 64;
        float* K2f = V1f + (long)n1 * 64;
        float* V2f = K2f + (long)n2 * 64;
        float* transf = V2f + (long)n2 * 64;
        int* deg1f = (int*)(transf + E);
        int* deg2f = deg1f + n1;
        int* cur1f = deg2f + n2;
        int* cur2f = cur1f + n1;
        int* el1 = (int*)K1f;
        int* el2 = (int*)K2f;
        int nmax = n1 > n2 ? n1 : n2;

        proj1_kernel<<<(n1 + 3) / 4, 256, 0, stream>>>(node1, n1, Wk, Wv, K1f, V1f);
        proj1_kernel<<<(n2 + 3) / 4, 256, 0, stream>>>(node2, n2, Wk, Wv, K2f, V2f);
        {
            long threads = (long)E * 16;
            int blocks = (int)((threads + 255) / 256);
            logit_kernel<<<blocks, 256, 0, stream>>>(K1f, K2f, seg1, seg2, transf, E);
        }
        zero_deg_kernel<<<(nmax + 255) / 256, 256, 0, stream>>>(deg1f, deg2f, n1, n2);
        hist_kernel<<<(E + 255) / 256, 256, 0, stream>>>(seg1, seg2, deg1f, deg2f, E);
        scan2_kernel<<<2, 1024, 0, stream>>>(deg1f, cur1f, n1, deg2f, cur2f, n2);
        bin_kernel<<<(E + 255) / 256, 256, 0, stream>>>(seg1, seg2, cur1f, cur2f, el1, el2, E);

        gather_out_kernel<<<(n1 + 3) / 4, 256, 0, stream>>>(
            n1, cur1f, deg1f, el1, transf, seg2, V2f, e1, msg1, Wo, bo, invT);
        gather_out_kernel<<<(n2 + 3) / 4, 256, 0, stream>>>(
            n2, cur2f, deg2f, el2, transf, seg1, V1f, e2, msg2, Wo, bo, invT);
    }
}

// Round 6
// 248.996 us; speedup vs baseline: 8.2142x; 1.0737x over previous
//
#include <hip/hip_runtime.h>
#include <math.h>

#define BSH 7              // 128 nodes per bucket
#define BSZ (1 << BSH)
#define MAXNB 256          // max buckets per side
#define PT_TILE 4096       // edges per partition block

__device__ __forceinline__ float readlane_f(float v, int l) {
    return __uint_as_float((unsigned)__builtin_amdgcn_readlane((int)__float_as_uint(v), l));
}
// f32 -> bf16 (round to nearest even)
__device__ __forceinline__ unsigned short f2b(float f) {
    unsigned u = __float_as_uint(f);
    return (unsigned short)((u + 0x7FFFu + ((u >> 16) & 1u)) >> 16);
}
__device__ __forceinline__ float blo(unsigned u) { return __uint_as_float(u << 16); }
__device__ __forceinline__ float bhi(unsigned u) { return __uint_as_float(u & 0xFFFF0000u); }

// ---------- fused projections -> bf16 K,V (both sides, one launch) ----------
__global__ void proj_kernel(const float* __restrict__ X1, int n1, int g1,
                            const float* __restrict__ X2, int n2,
                            const float* __restrict__ Wk,
                            const float* __restrict__ Wv,
                            unsigned short* __restrict__ K1, unsigned short* __restrict__ V1,
                            unsigned short* __restrict__ K2, unsigned short* __restrict__ V2) {
    __shared__ float sWk[64 * 64];
    __shared__ float sWv[64 * 64];
    int tid = threadIdx.x;
    for (int i = tid; i < 4096; i += blockDim.x) { sWk[i] = Wk[i]; sWv[i] = Wv[i]; }
    __syncthreads();
    int wave = tid >> 6, lane = tid & 63;
    const float* X; unsigned short* K; unsigned short* V; int N, nd0;
    if ((int)blockIdx.x < g1) { X = X1; K = K1; V = V1; N = n1; nd0 = blockIdx.x * 4; }
    else { X = X2; K = K2; V = V2; N = n2; nd0 = (blockIdx.x - g1) * 4; }
    int n = nd0 + wave;
    if (n >= N) return;
    float x = X[(long)n * 64 + lane];
    float ak = 0.f, av = 0.f;
#pragma unroll
    for (int k = 0; k < 64; ++k) {
        float xv = __shfl(x, k);
        ak = fmaf(xv, sWk[k * 64 + lane], ak);
        av = fmaf(xv, sWv[k * 64 + lane], av);
    }
    K[(long)n * 64 + lane] = f2b(ak);
    V[(long)n * 64 + lane] = f2b(av);
}

// ---------- edge logits (bf16 K rows) ----------
__global__ void logit_kernel(const unsigned short* __restrict__ K1,
                             const unsigned short* __restrict__ K2,
                             const int* __restrict__ seg1, const int* __restrict__ seg2,
                             float* __restrict__ trans, int E) {
    int tid = blockIdx.x * blockDim.x + threadIdx.x;
    int e = tid >> 4, g = tid & 15;
    if (e >= E) return;
    int i1 = seg1[e], i2 = seg2[e];
    uint2 a = *(const uint2*)(K1 + (long)i1 * 64 + g * 4);
    uint2 b = *(const uint2*)(K2 + (long)i2 * 64 + g * 4);
    float d = blo(a.x) * blo(b.x);
    d = fmaf(bhi(a.x), bhi(b.x), d);
    d = fmaf(blo(a.y), blo(b.y), d);
    d = fmaf(bhi(a.y), bhi(b.y), d);
    d += __shfl_xor(d, 1);
    d += __shfl_xor(d, 2);
    d += __shfl_xor(d, 4);
    d += __shfl_xor(d, 8);
    if (g == 0) trans[e] = d;
}

// ---------- bucket histogram ----------
__global__ void zero_small_kernel(int* b1, int* b2, int nb1, int nb2) {
    int i = threadIdx.x;
    if (i < nb1) b1[i] = 0;
    if (i < nb2) b2[i] = 0;
}

__global__ void bucket_count_kernel(const int* __restrict__ seg1, const int* __restrict__ seg2,
                                    int E, int* bcnt1, int* bcnt2, int nb1, int nb2) {
    __shared__ int c1[MAXNB], c2[MAXNB];
    int tid = threadIdx.x;
    for (int i = tid; i < MAXNB; i += blockDim.x) { c1[i] = 0; c2[i] = 0; }
    __syncthreads();
    for (int i = blockIdx.x * blockDim.x + tid; i < E; i += gridDim.x * blockDim.x) {
        atomicAdd(&c1[seg1[i] >> BSH], 1);
        atomicAdd(&c2[seg2[i] >> BSH], 1);
    }
    __syncthreads();
    for (int i = tid; i < nb1; i += blockDim.x) if (c1[i]) atomicAdd(&bcnt1[i], c1[i]);
    for (int i = tid; i < nb2; i += blockDim.x) if (c2[i]) atomicAdd(&bcnt2[i], c2[i]);
}

// ---------- scan bucket counts ----------
__global__ void bucket_scan_kernel(const int* __restrict__ bcnt1, const int* __restrict__ bcnt2,
                                   int* bb1, int* bb2, int* bcur1, int* bcur2,
                                   int nb1, int nb2, int E) {
    __shared__ int tmp[MAXNB];
    int t = threadIdx.x;
    int v1 = (t < nb1) ? bcnt1[t] : 0;
    tmp[t] = v1;
    __syncthreads();
    for (int off = 1; off < MAXNB; off <<= 1) {
        int x = (t >= off) ? tmp[t - off] : 0;
        __syncthreads();
        tmp[t] += x;
        __syncthreads();
    }
    if (t < nb1) { int excl = tmp[t] - v1; bb1[t] = excl; bcur1[t] = excl; }
    if (t == 0) bb1[nb1] = E;
    __syncthreads();
    int v2 = (t < nb2) ? bcnt2[t] : 0;
    tmp[t] = v2;
    __syncthreads();
    for (int off = 1; off < MAXNB; off <<= 1) {
        int x = (t >= off) ? tmp[t - off] : 0;
        __syncthreads();
        tmp[t] += x;
        __syncthreads();
    }
    if (t < nb2) { int excl = tmp[t] - v2; bb2[t] = excl; bcur2[t] = excl; }
    if (t == 0) bb2[nb2] = E;
}

// ---------- partition: emit (t, nodelocal<<25|j) records into bucket regions ----------
__global__ void partition_kernel(const int* __restrict__ seg1, const int* __restrict__ seg2,
                                 const float* __restrict__ trans, int E,
                                 int* bcur1, int* bcur2,
                                 float2* __restrict__ tmp1, float2* __restrict__ tmp2) {
    __shared__ int c1[MAXNB], c2[MAXNB];
    int tid = threadIdx.x;
    int base = blockIdx.x * PT_TILE;
    int end = base + PT_TILE;
    if (end > E) end = E;
    for (int i = tid; i < MAXNB; i += blockDim.x) { c1[i] = 0; c2[i] = 0; }
    __syncthreads();
    for (int i = base + tid; i < end; i += blockDim.x) {
        atomicAdd(&c1[seg1[i] >> BSH], 1);
        atomicAdd(&c2[seg2[i] >> BSH], 1);
    }
    __syncthreads();
    for (int i = tid; i < MAXNB; i += blockDim.x) {
        int n = c1[i]; c1[i] = n ? atomicAdd(&bcur1[i], n) : 0;
        n = c2[i];     c2[i] = n ? atomicAdd(&bcur2[i], n) : 0;
    }
    __syncthreads();
    for (int i = base + tid; i < end; i += blockDim.x) {
        int s1 = seg1[i], s2 = seg2[i];
        float t = trans[i];
        int p = atomicAdd(&c1[s1 >> BSH], 1);
        tmp1[p] = make_float2(t, __int_as_float(((s1 & (BSZ - 1)) << 25) | s2));
        int q = atomicAdd(&c2[s2 >> BSH], 1);
        tmp2[q] = make_float2(t, __int_as_float(((s2 & (BSZ - 1)) << 25) | s1));
    }
}

// ---------- bin2 (fused both sides): bucket records -> node-sorted CSR (t, j) ----------
__global__ void bin2_kernel(const float2* __restrict__ tmp1, const int* __restrict__ bb1,
                            int n1, int* __restrict__ cur1, int* __restrict__ deg1,
                            float2* __restrict__ csr1,
                            const float2* __restrict__ tmp2, const int* __restrict__ bb2,
                            int n2, int* __restrict__ cur2, int* __restrict__ deg2,
                            float2* __restrict__ csr2, int nb1) {
    __shared__ int cnt[BSZ];
    __shared__ int off[BSZ];
    __shared__ int sc[BSZ];
    int b = blockIdx.x;
    const float2* tmp; const int* bb; int n; int* cur; int* deg; float2* csr;
    if (b < nb1) { tmp = tmp1; bb = bb1; n = n1; cur = cur1; deg = deg1; csr = csr1; }
    else { b -= nb1; tmp = tmp2; bb = bb2; n = n2; cur = cur2; deg = deg2; csr = csr2; }
    int tid = threadIdx.x;
    int node0 = b << BSH;
    int s = bb[b], e_end = bb[b + 1];
    for (int i = tid; i < BSZ; i += blockDim.x) cnt[i] = 0;
    __syncthreads();
    for (int i = s + tid; i < e_end; i += blockDim.x)
        atomicAdd(&cnt[((unsigned)__float_as_int(tmp[i].y)) >> 25], 1);
    __syncthreads();
    if (tid < BSZ) sc[tid] = cnt[tid];
    __syncthreads();
    for (int o = 1; o < BSZ; o <<= 1) {
        int x = (tid >= o && tid < BSZ) ? sc[tid - o] : 0;
        __syncthreads();
        if (tid < BSZ) sc[tid] += x;
        __syncthreads();
    }
    if (tid < BSZ) {
        int excl = sc[tid] - cnt[tid] + s;
        off[tid] = excl;
        int node = node0 + tid;
        if (node < n) { cur[node] = excl; deg[node] = cnt[tid]; }
    }
    __syncthreads();
    for (int i = s + tid; i < e_end; i += blockDim.x) {
        float2 r = tmp[i];
        unsigned pay = (unsigned)__float_as_int(r.y);
        int pos = atomicAdd(&off[pay >> 25], 1);
        csr[pos] = make_float2(r.x, __int_as_float((int)(pay & 0x1FFFFFFu)));
    }
}

// ---------- gather (fused both sides): softmax + 4-edge-in-flight bf16 V gather + Wo ----------
__global__ void gather_ms_kernel(int n1, int n2, int g1,
                                 const int* __restrict__ cur1, const int* __restrict__ deg1,
                                 const float2* __restrict__ csr1,
                                 const unsigned short* __restrict__ Vb2,
                                 float2* __restrict__ minv1, float* __restrict__ msg1,
                                 const int* __restrict__ cur2, const int* __restrict__ deg2,
                                 const float2* __restrict__ csr2,
                                 const unsigned short* __restrict__ Vb1,
                                 float2* __restrict__ minv2, float* __restrict__ msg2,
                                 const float* __restrict__ Wo, const float* __restrict__ bo,
                                 float invT) {
    __shared__ float sW[64 * 64];
    int tid = threadIdx.x;
    for (int i = tid; i < 4096; i += blockDim.x) sW[i] = Wo[i];
    __syncthreads();
    int wave = tid >> 6, lane = tid & 63;
    const int *cur, *deg; const float2* csr; const unsigned short* V; float2* minv; float* msg;
    int N, nd0;
    if ((int)blockIdx.x < g1) {
        cur = cur1; deg = deg1; csr = csr1; V = Vb2; minv = minv1; msg = msg1;
        N = n1; nd0 = blockIdx.x * 4;
    } else {
        cur = cur2; deg = deg2; csr = csr2; V = Vb1; minv = minv2; msg = msg2;
        N = n2; nd0 = (blockIdx.x - g1) * 4;
    }
    int nd = nd0 + wave;
    if (nd >= N) return;
    int d = deg[nd];
    int start = cur[nd];
    int g = lane >> 4, l = lane & 15;
    float4 acc = make_float4(0.f, 0.f, 0.f, 0.f);
    if (d > 0) {
        float t0 = -INFINITY, t1 = -INFINITY, t2 = -INFINITY;
        int j0 = 0, j1 = 0, j2 = 0;
        if (lane < d)       { float2 r = csr[start + lane];       t0 = r.x; j0 = __float_as_int(r.y); }
        if (lane + 64 < d)  { float2 r = csr[start + lane + 64];  t1 = r.x; j1 = __float_as_int(r.y); }
        if (lane + 128 < d) { float2 r = csr[start + lane + 128]; t2 = r.x; j2 = __float_as_int(r.y); }
        float m = fmaxf(fmaxf(t0, t1), t2);
        for (int k = 192 + lane; k < d; k += 64) m = fmaxf(m, csr[start + k].x);
        m = fmaxf(m, __shfl_xor(m, 1));
        m = fmaxf(m, __shfl_xor(m, 2));
        m = fmaxf(m, __shfl_xor(m, 4));
        m = fmaxf(m, __shfl_xor(m, 8));
        m = fmaxf(m, __shfl_xor(m, 16));
        m = fmaxf(m, __shfl_xor(m, 32));
        float p0 = (lane < d)       ? __expf((t0 - m) * invT) : 0.f;
        float p1 = (lane + 64 < d)  ? __expf((t1 - m) * invT) : 0.f;
        float p2 = (lane + 128 < d) ? __expf((t2 - m) * invT) : 0.f;
        float s = p0 + p1 + p2;
        for (int k = 192 + lane; k < d; k += 64) s += __expf((csr[start + k].x - m) * invT);
        s += __shfl_xor(s, 1);
        s += __shfl_xor(s, 2);
        s += __shfl_xor(s, 4);
        s += __shfl_xor(s, 8);
        s += __shfl_xor(s, 16);
        s += __shfl_xor(s, 32);
        float inv = 1.f / (s + 1e-8f);
        if (lane == 0) minv[nd] = make_float2(m, inv);
        float w0 = p0 * inv, w1 = p1 * inv, w2 = p2 * inv;
        // 4 edges in flight: group g handles edge k+g; 16 lanes x 4 bf16 per row
        int c0 = d < 64 ? d : 64;
#pragma unroll 4
        for (int k = 0; k < c0; k += 4) {
            float w = __shfl(w0, k + g);
            int j = __shfl(j0, k + g);
            uint2 v = *(const uint2*)(V + (long)j * 64 + l * 4);
            acc.x = fmaf(w, blo(v.x), acc.x);
            acc.y = fmaf(w, bhi(v.x), acc.y);
            acc.z = fmaf(w, blo(v.y), acc.z);
            acc.w = fmaf(w, bhi(v.y), acc.w);
        }
        if (d > 64) {
            int c1 = (d - 64) < 64 ? (d - 64) : 64;
#pragma unroll 4
            for (int k = 0; k < c1; k += 4) {
                float w = __shfl(w1, k + g);
                int j = __shfl(j1, k + g);
                uint2 v = *(const uint2*)(V + (long)j * 64 + l * 4);
                acc.x = fmaf(w, blo(v.x), acc.x);
                acc.y = fmaf(w, bhi(v.x), acc.y);
                acc.z = fmaf(w, blo(v.y), acc.z);
                acc.w = fmaf(w, bhi(v.y), acc.w);
            }
        }
        if (d > 128) {
            int c2 = (d - 128) < 64 ? (d - 128) : 64;
#pragma unroll 4
            for (int k = 0; k < c2; k += 4) {
                float w = __shfl(w2, k + g);
                int j = __shfl(j2, k + g);
                uint2 v = *(const uint2*)(V + (long)j * 64 + l * 4);
                acc.x = fmaf(w, blo(v.x), acc.x);
                acc.y = fmaf(w, bhi(v.x), acc.y);
                acc.z = fmaf(w, blo(v.y), acc.z);
                acc.w = fmaf(w, bhi(v.y), acc.w);
            }
        }
        for (int base = 192; base < d; base += 64) {
            int k = base + lane;
            float wr = 0.f; int jr = 0;
            if (k < d) {
                float2 r = csr[start + k];
                wr = __expf((r.x - m) * invT) * inv;
                jr = __float_as_int(r.y);
            }
            int cc = (d - base) < 64 ? (d - base) : 64;
            for (int k2 = 0; k2 < cc; k2 += 4) {
                float w = __shfl(wr, k2 + g);
                int j = __shfl(jr, k2 + g);
                uint2 v = *(const uint2*)(V + (long)j * 64 + l * 4);
                acc.x = fmaf(w, blo(v.x), acc.x);
                acc.y = fmaf(w, bhi(v.x), acc.y);
                acc.z = fmaf(w, blo(v.y), acc.z);
                acc.w = fmaf(w, bhi(v.y), acc.w);
            }
        }
        // reduce partial sums across the 4 groups
        acc.x += __shfl_xor(acc.x, 16); acc.y += __shfl_xor(acc.y, 16);
        acc.z += __shfl_xor(acc.z, 16); acc.w += __shfl_xor(acc.w, 16);
        acc.x += __shfl_xor(acc.x, 32); acc.y += __shfl_xor(acc.y, 32);
        acc.z += __shfl_xor(acc.z, 32); acc.w += __shfl_xor(acc.w, 32);
    }
    // fused Wo GEMM + bias + leaky relu; lane kk (<16) holds components 4kk..4kk+3
    float o = bo[lane];
#pragma unroll
    for (int kk = 0; kk < 16; ++kk) {
        float a0 = readlane_f(acc.x, kk);
        float a1 = readlane_f(acc.y, kk);
        float a2 = readlane_f(acc.z, kk);
        float a3 = readlane_f(acc.w, kk);
        o = fmaf(a0, sW[(4 * kk + 0) * 64 + lane], o);
        o = fmaf(a1, sW[(4 * kk + 1) * 64 + lane], o);
        o = fmaf(a2, sW[(4 * kk + 2) * 64 + lane], o);
        o = fmaf(a3, sW[(4 * kk + 3) * 64 + lane], o);
    }
    o = (o >= 0.f) ? o : 0.01f * o;
    msg[(long)nd * 64 + lane] = o;
}

// ---------- coalesced edge weights ----------
__global__ void edge_w_kernel(const float* __restrict__ trans,
                              const int* __restrict__ seg1, const int* __restrict__ seg2,
                              const float2* __restrict__ minv1, const float2* __restrict__ minv2,
                              float* __restrict__ e1, float* __restrict__ e2,
                              int E, float invT) {
    int e = blockIdx.x * blockDim.x + threadIdx.x;
    if (e >= E) return;
    float t = trans[e];
    float2 a = minv1[seg1[e]];
    float2 b = minv2[seg2[e]];
    e1[e] = __expf((t - a.x) * invT) * a.y;
    e2[e] = __expf((t - b.x) * invT) * b.y;
}

// ---------- fallback path kernels (R2-proven, f32) ----------
__global__ void proj1_kernel(const float* __restrict__ X, int N,
                             const float* __restrict__ Wk,
                             const float* __restrict__ Wv,
                             float* __restrict__ K, float* __restrict__ V) {
    __shared__ float sWk[64 * 64];
    __shared__ float sWv[64 * 64];
    int tid = threadIdx.x;
    for (int i = tid; i < 4096; i += blockDim.x) { sWk[i] = Wk[i]; sWv[i] = Wv[i]; }
    __syncthreads();
    int wave = tid >> 6, lane = tid & 63;
    int wpb = blockDim.x >> 6;
    for (int n = blockIdx.x * wpb + wave; n < N; n += gridDim.x * wpb) {
        float x = X[n * 64 + lane];
        float ak = 0.f, av = 0.f;
#pragma unroll
        for (int k = 0; k < 64; ++k) {
            float xv = __shfl(x, k);
            ak = fmaf(xv, sWk[k * 64 + lane], ak);
            av = fmaf(xv, sWv[k * 64 + lane], av);
        }
        K[n * 64 + lane] = ak;
        V[n * 64 + lane] = av;
    }
}
__global__ void logit1_kernel(const float* __restrict__ K1, const float* __restrict__ K2,
                              const int* __restrict__ seg1, const int* __restrict__ seg2,
                              float* __restrict__ trans, int E) {
    int tid = blockIdx.x * blockDim.x + threadIdx.x;
    int e = tid >> 4, g = tid & 15;
    if (e >= E) return;
    int i1 = seg1[e], i2 = seg2[e];
    float4 a = ((const float4*)(K1 + (long)i1 * 64))[g];
    float4 b = ((const float4*)(K2 + (long)i2 * 64))[g];
    float d = a.x * b.x + a.y * b.y + a.z * b.z + a.w * b.w;
    d += __shfl_xor(d, 1);
    d += __shfl_xor(d, 2);
    d += __shfl_xor(d, 4);
    d += __shfl_xor(d, 8);
    if (g == 0) trans[e] = d;
}
__global__ void zero_deg_kernel(int* d1, int* d2, int n1, int n2) {
    int i = blockIdx.x * blockDim.x + threadIdx.x;
    if (i < n1) d1[i] = 0;
    if (i < n2) d2[i] = 0;
}
__global__ void hist_kernel(const int* __restrict__ seg1, const int* __restrict__ seg2,
                            int* deg1, int* deg2, int E) {
    int e = blockIdx.x * blockDim.x + threadIdx.x;
    if (e >= E) return;
    atomicAdd(&deg1[seg1[e]], 1);
    atomicAdd(&deg2[seg2[e]], 1);
}
__global__ void scan2_kernel(const int* __restrict__ d1, int* __restrict__ c1, int n1,
                             const int* __restrict__ d2, int* __restrict__ c2, int n2) {
    const int* deg = blockIdx.x ? d2 : d1;
    int* cur = blockIdx.x ? c2 : c1;
    int n = blockIdx.x ? n2 : n1;
    __shared__ int tmp[1024];
    __shared__ int s_carry;
    int t = threadIdx.x;
    if (t == 0) s_carry = 0;
    __syncthreads();
    for (int base = 0; base < n; base += 1024) {
        int idx = base + t;
        int v = (idx < n) ? deg[idx] : 0;
        tmp[t] = v;
        __syncthreads();
        for (int off = 1; off < 1024; off <<= 1) {
            int x = (t >= off) ? tmp[t - off] : 0;
            __syncthreads();
            tmp[t] += x;
            __syncthreads();
        }
        int excl = tmp[t] - v + s_carry;
        if (idx < n) cur[idx] = excl;
        __syncthreads();
        if (t == 0) s_carry += tmp[1023];
        __syncthreads();
    }
}
__global__ void bin_kernel(const int* __restrict__ seg1, const int* __restrict__ seg2,
                           int* cur1, int* cur2,
                           int* __restrict__ el1, int* __restrict__ el2, int E) {
    int e = blockIdx.x * blockDim.x + threadIdx.x;
    if (e >= E) return;
    int p1 = atomicAdd(&cur1[seg1[e]], 1);
    el1[p1] = e;
    int p2 = atomicAdd(&cur2[seg2[e]], 1);
    el2[p2] = e;
}
__global__ void gather_out_kernel(int N, const int* __restrict__ cur, const int* __restrict__ deg,
                                  const int* __restrict__ el, const float* __restrict__ trans,
                                  const int* __restrict__ segOther, const float* __restrict__ Vother,
                                  float* __restrict__ e_out, float* __restrict__ msg_out,
                                  const float* __restrict__ Wo, const float* __restrict__ bo,
                                  float invT) {
    __shared__ float sW[64 * 64];
    int tid = threadIdx.x;
    for (int i = tid; i < 4096; i += blockDim.x) sW[i] = Wo[i];
    __syncthreads();
    int wave = tid >> 6, lane = tid & 63;
    int wpb = blockDim.x >> 6;
    int node = blockIdx.x * wpb + wave;
    if (node >= N) return;
    int d = deg[node];
    int start = cur[node] - d;
    float acc = 0.f;
    if (d > 0) {
        float m = -INFINITY;
        for (int k = lane; k < d; k += 64) m = fmaxf(m, trans[el[start + k]]);
        m = fmaxf(m, __shfl_xor(m, 1));
        m = fmaxf(m, __shfl_xor(m, 2));
        m = fmaxf(m, __shfl_xor(m, 4));
        m = fmaxf(m, __shfl_xor(m, 8));
        m = fmaxf(m, __shfl_xor(m, 16));
        m = fmaxf(m, __shfl_xor(m, 32));
        float s = 0.f;
        for (int k = lane; k < d; k += 64) s += __expf((trans[el[start + k]] - m) * invT);
        s += __shfl_xor(s, 1);
        s += __shfl_xor(s, 2);
        s += __shfl_xor(s, 4);
        s += __shfl_xor(s, 8);
        s += __shfl_xor(s, 16);
        s += __shfl_xor(s, 32);
        float inv = 1.f / (s + 1e-8f);
        for (int base = 0; base < d; base += 64) {
            int k = base + lane;
            float w = 0.f;
            int j = 0;
            if (k < d) {
                int e = el[start + k];
                w = __expf((trans[e] - m) * invT) * inv;
                e_out[e] = w;
                j = segOther[e];
            }
            int cnt = (d - base < 64) ? (d - base) : 64;
            for (int q = 0; q < cnt; ++q) {
                float wq = __shfl(w, q);
                int jq = __shfl(j, q);
                acc = fmaf(wq, Vother[(long)jq * 64 + lane], acc);
            }
        }
    }
    float o = bo[lane];
#pragma unroll
    for (int k = 0; k < 64; ++k) {
        float xv = __shfl(acc, k);
        o = fmaf(xv, sW[k * 64 + lane], o);
    }
    o = (o >= 0.f) ? o : 0.01f * o;
    msg_out[(long)node * 64 + lane] = o;
}

extern "C" void kernel_launch(void* const* d_in, const int* in_sizes, int n_in,
                              void* d_out, int out_size, void* d_ws, size_t ws_size,
                              hipStream_t stream) {
    const float* node1 = (const float*)d_in[0];
    const int* seg1 = (const int*)d_in[1];
    const float* node2 = (const float*)d_in[3];
    const int* seg2 = (const int*)d_in[4];
    const float* Wk = (const float*)d_in[6];
    const float* Wv = (const float*)d_in[7];
    const float* Wo = (const float*)d_in[8];
    const float* bo = (const float*)d_in[9];

    int n1 = in_sizes[0] / 64;
    int n2 = in_sizes[3] / 64;
    int E = in_sizes[1];

    float* out = (float*)d_out;
    float* msg1 = out;
    float* msg2 = msg1 + (long)n1 * 64;
    float* e1 = msg2 + (long)n2 * 64;
    float* e2 = e1 + E;

    const float invT = 1.0f / sqrtf(64.0f);
    int nb1 = (n1 + BSZ - 1) >> BSH;
    int nb2 = (n2 + BSZ - 1) >> BSH;
    long Epad = (E + 1) & ~1L;

    // ---- fast-path layout (8B alignment for float2 arrays; bf16 K/V) ----
    float* ws = (float*)d_ws;
    float2* csr1 = (float2*)ws;                         // E records
    float2* csr2 = csr1 + E;                            // E
    float2* tmp1 = csr2 + E;                            // E
    float2* tmp2 = tmp1 + E;                            // E
    float* trans = (float*)(tmp2 + E);                  // Epad
    float2* minv1 = (float2*)(trans + Epad);            // n1
    float2* minv2 = minv1 + n1;                         // n2
    unsigned short* Kb1 = (unsigned short*)(minv2 + n2);// n1*64 ushort
    unsigned short* Kb2 = Kb1 + (long)n1 * 64;          // n2*64
    unsigned short* Vb1 = Kb2 + (long)n2 * 64;          // n1*64
    unsigned short* Vb2 = Vb1 + (long)n1 * 64;          // n2*64
    int* deg1 = (int*)(Vb2 + (long)n2 * 64);            // n1
    int* deg2 = deg1 + n1;                              // n2
    int* cur1 = deg2 + n2;                              // n1
    int* cur2 = cur1 + n1;                              // n2
    int* bb1 = cur2 + n2;                               // nb1+1
    int* bb2 = bb1 + nb1 + 1;                           // nb2+1
    int* bcur1 = bb2 + nb2 + 1;                         // nb1
    int* bcur2 = bcur1 + nb1;                           // nb2
    int* bcnt1 = bcur2 + nb2;                           // nb1
    int* bcnt2 = bcnt1 + nb1;                           // nb2
    long fp_words = 8L * E + Epad + 2L * (n1 + n2)      // csr/tmp + trans + minv
                  + 64L * (n1 + n2)                     // bf16 K,V both sides
                  + 2L * (n1 + n2)                      // deg, cur
                  + 3L * (nb1 + nb2) + 2;
    bool fast = (E <= (1 << 20)) && (nb1 <= MAXNB) && (nb2 <= MAXNB)
             && (n1 < (1 << 25)) && (n2 < (1 << 25))
             && ((size_t)fp_words * 4 <= ws_size);

    if (fast) {
        int g1p = (n1 + 3) / 4, g2p = (n2 + 3) / 4;
        proj_kernel<<<g1p + g2p, 256, 0, stream>>>(node1, n1, g1p, node2, n2,
                                                   Wk, Wv, Kb1, Vb1, Kb2, Vb2);
        {
            long threads = (long)E * 16;
            int blocks = (int)((threads + 255) / 256);
            logit_kernel<<<blocks, 256, 0, stream>>>(Kb1, Kb2, seg1, seg2, trans, E);
        }
        zero_small_kernel<<<1, 256, 0, stream>>>(bcnt1, bcnt2, nb1, nb2);
        bucket_count_kernel<<<512, 256, 0, stream>>>(seg1, seg2, E, bcnt1, bcnt2, nb1, nb2);
        bucket_scan_kernel<<<1, MAXNB, 0, stream>>>(bcnt1, bcnt2, bb1, bb2, bcur1, bcur2,
                                                    nb1, nb2, E);
        partition_kernel<<<(E + PT_TILE - 1) / PT_TILE, 256, 0, stream>>>(
            seg1, seg2, trans, E, bcur1, bcur2, tmp1, tmp2);
        bin2_kernel<<<nb1 + nb2, 256, 0, stream>>>(tmp1, bb1, n1, cur1, deg1, csr1,
                                                   tmp2, bb2, n2, cur2, deg2, csr2, nb1);
        gather_ms_kernel<<<g1p + g2p, 256, 0, stream>>>(
            n1, n2, g1p, cur1, deg1, csr1, Vb2, minv1, msg1,
            cur2, deg2, csr2, Vb1, minv2, msg2, Wo, bo, invT);
        edge_w_kernel<<<(E + 255) / 256, 256, 0, stream>>>(
            trans, seg1, seg2, minv1, minv2, e1, e2, E, invT);
    } else {
        // fallback: R2-proven f32 path
        float* K1f = ws;
        float* V1f = K1f + (long)n1 * 64;
        float* K2f = V1f + (long)n1 * 64;
        float* V2f = K2f + (long)n2 * 64;
        float* transf = V2f + (long)n2 * 64;
        int* deg1f = (int*)(transf + E);
        int* deg2f = deg1f + n1;
        int* cur1f = deg2f + n2;
        int* cur2f = cur1f + n1;
        int* el1 = (int*)K1f;
        int* el2 = (int*)K2f;
        int nmax = n1 > n2 ? n1 : n2;

        proj1_kernel<<<(n1 + 3) / 4, 256, 0, stream>>>(node1, n1, Wk, Wv, K1f, V1f);
        proj1_kernel<<<(n2 + 3) / 4, 256, 0, stream>>>(node2, n2, Wk, Wv, K2f, V2f);
        {
            long threads = (long)E * 16;
            int blocks = (int)((threads + 255) / 256);
            logit1_kernel<<<blocks, 256, 0, stream>>>(K1f, K2f, seg1, seg2, transf, E);
        }
        zero_deg_kernel<<<(nmax + 255) / 256, 256, 0, stream>>>(deg1f, deg2f, n1, n2);
        hist_kernel<<<(E + 255) / 256, 256, 0, stream>>>(seg1, seg2, deg1f, deg2f, E);
        scan2_kernel<<<2, 1024, 0, stream>>>(deg1f, cur1f, n1, deg2f, cur2f, n2);
        bin_kernel<<<(E + 255) / 256, 256, 0, stream>>>(seg1, seg2, cur1f, cur2f, el1, el2, E);

        gather_out_kernel<<<(n1 + 3) / 4, 256, 0, stream>>>(
            n1, cur1f, deg1f, el1, transf, seg2, V2f, e1, msg1, Wo, bo, invT);
        gather_out_kernel<<<(n2 + 3) / 4, 256, 0, stream>>>(
            n2, cur2f, deg2f, el2, transf, seg1, V1f, e2, msg2, Wo, bo, invT);
    }
}

// Round 7
// 248.890 us; speedup vs baseline: 8.2177x; 1.0004x over previous
//
#include <hip/hip_runtime.h>
#include <math.h>

#define BSH 7              // 128 nodes per bucket
#define BSZ (1 << BSH)
#define MAXNB 256          // max buckets per side
#define PT_TILE 4096       // edges per partition block

__device__ __forceinline__ float readlane_f(float v, int l) {
    return __uint_as_float((unsigned)__builtin_amdgcn_readlane((int)__float_as_uint(v), l));
}
// f32 -> bf16 (round to nearest even)
__device__ __forceinline__ unsigned short f2b(float f) {
    unsigned u = __float_as_uint(f);
    return (unsigned short)((u + 0x7FFFu + ((u >> 16) & 1u)) >> 16);
}
__device__ __forceinline__ float blo(unsigned u) { return __uint_as_float(u << 16); }
__device__ __forceinline__ float bhi(unsigned u) { return __uint_as_float(u & 0xFFFF0000u); }

// ---------- persistent fused projections -> bf16 K,V; block 0 zeroes bucket counters ----------
__global__ void proj_kernel(const float* __restrict__ X1, int n1,
                            const float* __restrict__ X2, int n2,
                            const float* __restrict__ Wk,
                            const float* __restrict__ Wv,
                            unsigned short* __restrict__ K1, unsigned short* __restrict__ V1,
                            unsigned short* __restrict__ K2, unsigned short* __restrict__ V2,
                            int* bcnt1, int* bcnt2, int nb1, int nb2) {
    __shared__ float sWk[64 * 64];
    __shared__ float sWv[64 * 64];
    int tid = threadIdx.x;
    if (blockIdx.x == 0) {
        for (int i = tid; i < nb1; i += blockDim.x) bcnt1[i] = 0;
        for (int i = tid; i < nb2; i += blockDim.x) bcnt2[i] = 0;
    }
    for (int i = tid; i < 4096; i += blockDim.x) { sWk[i] = Wk[i]; sWv[i] = Wv[i]; }
    __syncthreads();
    int wave = tid >> 6, lane = tid & 63;
    int wpb = blockDim.x >> 6;
    int total = n1 + n2;
    for (int idx = blockIdx.x * wpb + wave; idx < total; idx += gridDim.x * wpb) {
        const float* X; unsigned short* K; unsigned short* V; long r;
        if (idx < n1) { X = X1; K = K1; V = V1; r = idx; }
        else { X = X2; K = K2; V = V2; r = idx - n1; }
        float x = X[r * 64 + lane];
        float ak = 0.f, av = 0.f;
#pragma unroll
        for (int k = 0; k < 64; ++k) {
            float xv = __shfl(x, k);
            ak = fmaf(xv, sWk[k * 64 + lane], ak);
            av = fmaf(xv, sWv[k * 64 + lane], av);
        }
        K[r * 64 + lane] = f2b(ak);
        V[r * 64 + lane] = f2b(av);
    }
}

// ---------- edge logits (bf16 K rows) ----------
__global__ void logit_kernel(const unsigned short* __restrict__ K1,
                             const unsigned short* __restrict__ K2,
                             const int* __restrict__ seg1, const int* __restrict__ seg2,
                             float* __restrict__ trans, int E) {
    int tid = blockIdx.x * blockDim.x + threadIdx.x;
    int e = tid >> 4, g = tid & 15;
    if (e >= E) return;
    int i1 = seg1[e], i2 = seg2[e];
    uint2 a = *(const uint2*)(K1 + (long)i1 * 64 + g * 4);
    uint2 b = *(const uint2*)(K2 + (long)i2 * 64 + g * 4);
    float d = blo(a.x) * blo(b.x);
    d = fmaf(bhi(a.x), bhi(b.x), d);
    d = fmaf(blo(a.y), blo(b.y), d);
    d = fmaf(bhi(a.y), bhi(b.y), d);
    d += __shfl_xor(d, 1);
    d += __shfl_xor(d, 2);
    d += __shfl_xor(d, 4);
    d += __shfl_xor(d, 8);
    if (g == 0) trans[e] = d;
}

// ---------- bucket histogram ----------
__global__ void bucket_count_kernel(const int* __restrict__ seg1, const int* __restrict__ seg2,
                                    int E, int* bcnt1, int* bcnt2, int nb1, int nb2) {
    __shared__ int c1[MAXNB], c2[MAXNB];
    int tid = threadIdx.x;
    for (int i = tid; i < MAXNB; i += blockDim.x) { c1[i] = 0; c2[i] = 0; }
    __syncthreads();
    for (int i = blockIdx.x * blockDim.x + tid; i < E; i += gridDim.x * blockDim.x) {
        atomicAdd(&c1[seg1[i] >> BSH], 1);
        atomicAdd(&c2[seg2[i] >> BSH], 1);
    }
    __syncthreads();
    for (int i = tid; i < nb1; i += blockDim.x) if (c1[i]) atomicAdd(&bcnt1[i], c1[i]);
    for (int i = tid; i < nb2; i += blockDim.x) if (c2[i]) atomicAdd(&bcnt2[i], c2[i]);
}

// ---------- scan bucket counts ----------
__global__ void bucket_scan_kernel(const int* __restrict__ bcnt1, const int* __restrict__ bcnt2,
                                   int* bb1, int* bb2, int* bcur1, int* bcur2,
                                   int nb1, int nb2, int E) {
    __shared__ int tmp[MAXNB];
    int t = threadIdx.x;
    int v1 = (t < nb1) ? bcnt1[t] : 0;
    tmp[t] = v1;
    __syncthreads();
    for (int off = 1; off < MAXNB; off <<= 1) {
        int x = (t >= off) ? tmp[t - off] : 0;
        __syncthreads();
        tmp[t] += x;
        __syncthreads();
    }
    if (t < nb1) { int excl = tmp[t] - v1; bb1[t] = excl; bcur1[t] = excl; }
    if (t == 0) bb1[nb1] = E;
    __syncthreads();
    int v2 = (t < nb2) ? bcnt2[t] : 0;
    tmp[t] = v2;
    __syncthreads();
    for (int off = 1; off < MAXNB; off <<= 1) {
        int x = (t >= off) ? tmp[t - off] : 0;
        __syncthreads();
        tmp[t] += x;
        __syncthreads();
    }
    if (t < nb2) { int excl = tmp[t] - v2; bb2[t] = excl; bcur2[t] = excl; }
    if (t == 0) bb2[nb2] = E;
}

// ---------- partition: emit (t, nodelocal<<25|j) records into bucket regions ----------
__global__ void partition_kernel(const int* __restrict__ seg1, const int* __restrict__ seg2,
                                 const float* __restrict__ trans, int E,
                                 int* bcur1, int* bcur2,
                                 float2* __restrict__ tmp1, float2* __restrict__ tmp2) {
    __shared__ int c1[MAXNB], c2[MAXNB];
    int tid = threadIdx.x;
    int base = blockIdx.x * PT_TILE;
    int end = base + PT_TILE;
    if (end > E) end = E;
    for (int i = tid; i < MAXNB; i += blockDim.x) { c1[i] = 0; c2[i] = 0; }
    __syncthreads();
    for (int i = base + tid; i < end; i += blockDim.x) {
        atomicAdd(&c1[seg1[i] >> BSH], 1);
        atomicAdd(&c2[seg2[i] >> BSH], 1);
    }
    __syncthreads();
    for (int i = tid; i < MAXNB; i += blockDim.x) {
        int n = c1[i]; c1[i] = n ? atomicAdd(&bcur1[i], n) : 0;
        n = c2[i];     c2[i] = n ? atomicAdd(&bcur2[i], n) : 0;
    }
    __syncthreads();
    for (int i = base + tid; i < end; i += blockDim.x) {
        int s1 = seg1[i], s2 = seg2[i];
        float t = trans[i];
        int p = atomicAdd(&c1[s1 >> BSH], 1);
        tmp1[p] = make_float2(t, __int_as_float(((s1 & (BSZ - 1)) << 25) | s2));
        int q = atomicAdd(&c2[s2 >> BSH], 1);
        tmp2[q] = make_float2(t, __int_as_float(((s2 & (BSZ - 1)) << 25) | s1));
    }
}

// ---------- bin2 (fused both sides): bucket records -> node-sorted CSR (t, j) ----------
__global__ void bin2_kernel(const float2* __restrict__ tmp1, const int* __restrict__ bb1,
                            int n1, int* __restrict__ cur1, int* __restrict__ deg1,
                            float2* __restrict__ csr1,
                            const float2* __restrict__ tmp2, const int* __restrict__ bb2,
                            int n2, int* __restrict__ cur2, int* __restrict__ deg2,
                            float2* __restrict__ csr2, int nb1) {
    __shared__ int cnt[BSZ];
    __shared__ int off[BSZ];
    __shared__ int sc[BSZ];
    int b = blockIdx.x;
    const float2* tmp; const int* bb; int n; int* cur; int* deg; float2* csr;
    if (b < nb1) { tmp = tmp1; bb = bb1; n = n1; cur = cur1; deg = deg1; csr = csr1; }
    else { b -= nb1; tmp = tmp2; bb = bb2; n = n2; cur = cur2; deg = deg2; csr = csr2; }
    int tid = threadIdx.x;
    int node0 = b << BSH;
    int s = bb[b], e_end = bb[b + 1];
    for (int i = tid; i < BSZ; i += blockDim.x) cnt[i] = 0;
    __syncthreads();
    for (int i = s + tid; i < e_end; i += blockDim.x)
        atomicAdd(&cnt[((unsigned)__float_as_int(tmp[i].y)) >> 25], 1);
    __syncthreads();
    if (tid < BSZ) sc[tid] = cnt[tid];
    __syncthreads();
    for (int o = 1; o < BSZ; o <<= 1) {
        int x = (tid >= o && tid < BSZ) ? sc[tid - o] : 0;
        __syncthreads();
        if (tid < BSZ) sc[tid] += x;
        __syncthreads();
    }
    if (tid < BSZ) {
        int excl = sc[tid] - cnt[tid] + s;
        off[tid] = excl;
        int node = node0 + tid;
        if (node < n) { cur[node] = excl; deg[node] = cnt[tid]; }
    }
    __syncthreads();
    for (int i = s + tid; i < e_end; i += blockDim.x) {
        float2 r = tmp[i];
        unsigned pay = (unsigned)__float_as_int(r.y);
        int pos = atomicAdd(&off[pay >> 25], 1);
        csr[pos] = make_float2(r.x, __int_as_float((int)(pay & 0x1FFFFFFu)));
    }
}

// ---------- persistent gather (both sides): softmax + 4-edge bf16 V gather + fused Wo ----------
__global__ void gather_ms_kernel(int n1, int n2,
                                 const int* __restrict__ cur1, const int* __restrict__ deg1,
                                 const float2* __restrict__ csr1,
                                 const unsigned short* __restrict__ Vb2,
                                 float2* __restrict__ minv1, float* __restrict__ msg1,
                                 const int* __restrict__ cur2, const int* __restrict__ deg2,
                                 const float2* __restrict__ csr2,
                                 const unsigned short* __restrict__ Vb1,
                                 float2* __restrict__ minv2, float* __restrict__ msg2,
                                 const float* __restrict__ Wo, const float* __restrict__ bo,
                                 float invT) {
    __shared__ float sW[64 * 64];
    int tid = threadIdx.x;
    for (int i = tid; i < 4096; i += blockDim.x) sW[i] = Wo[i];
    __syncthreads();
    int wave = tid >> 6, lane = tid & 63;
    int wpb = blockDim.x >> 6;
    int g = lane >> 4, l = lane & 15;
    int total = n1 + n2;
    for (int idx = blockIdx.x * wpb + wave; idx < total; idx += gridDim.x * wpb) {
        const int *cur, *deg; const float2* csr; const unsigned short* V;
        float2* minv; float* msg; int nd;
        if (idx < n1) {
            cur = cur1; deg = deg1; csr = csr1; V = Vb2; minv = minv1; msg = msg1; nd = idx;
        } else {
            cur = cur2; deg = deg2; csr = csr2; V = Vb1; minv = minv2; msg = msg2; nd = idx - n1;
        }
        int d = deg[nd];
        int start = cur[nd];
        float4 acc = make_float4(0.f, 0.f, 0.f, 0.f);
        if (d > 0) {
            float t0 = -INFINITY, t1 = -INFINITY, t2 = -INFINITY;
            int j0 = 0, j1 = 0, j2 = 0;
            if (lane < d)       { float2 r = csr[start + lane];       t0 = r.x; j0 = __float_as_int(r.y); }
            if (lane + 64 < d)  { float2 r = csr[start + lane + 64];  t1 = r.x; j1 = __float_as_int(r.y); }
            if (lane + 128 < d) { float2 r = csr[start + lane + 128]; t2 = r.x; j2 = __float_as_int(r.y); }
            float m = fmaxf(fmaxf(t0, t1), t2);
            for (int k = 192 + lane; k < d; k += 64) m = fmaxf(m, csr[start + k].x);
            m = fmaxf(m, __shfl_xor(m, 1));
            m = fmaxf(m, __shfl_xor(m, 2));
            m = fmaxf(m, __shfl_xor(m, 4));
            m = fmaxf(m, __shfl_xor(m, 8));
            m = fmaxf(m, __shfl_xor(m, 16));
            m = fmaxf(m, __shfl_xor(m, 32));
            float p0 = (lane < d)       ? __expf((t0 - m) * invT) : 0.f;
            float p1 = (lane + 64 < d)  ? __expf((t1 - m) * invT) : 0.f;
            float p2 = (lane + 128 < d) ? __expf((t2 - m) * invT) : 0.f;
            float s = p0 + p1 + p2;
            for (int k = 192 + lane; k < d; k += 64) s += __expf((csr[start + k].x - m) * invT);
            s += __shfl_xor(s, 1);
            s += __shfl_xor(s, 2);
            s += __shfl_xor(s, 4);
            s += __shfl_xor(s, 8);
            s += __shfl_xor(s, 16);
            s += __shfl_xor(s, 32);
            float inv = 1.f / (s + 1e-8f);
            if (lane == 0) minv[nd] = make_float2(m, inv);
            float w0 = p0 * inv, w1 = p1 * inv, w2 = p2 * inv;
            int c0 = d < 64 ? d : 64;
#pragma unroll 4
            for (int k = 0; k < c0; k += 4) {
                float w = __shfl(w0, k + g);
                int j = __shfl(j0, k + g);
                uint2 v = *(const uint2*)(V + (long)j * 64 + l * 4);
                acc.x = fmaf(w, blo(v.x), acc.x);
                acc.y = fmaf(w, bhi(v.x), acc.y);
                acc.z = fmaf(w, blo(v.y), acc.z);
                acc.w = fmaf(w, bhi(v.y), acc.w);
            }
            if (d > 64) {
                int c1 = (d - 64) < 64 ? (d - 64) : 64;
#pragma unroll 4
                for (int k = 0; k < c1; k += 4) {
                    float w = __shfl(w1, k + g);
                    int j = __shfl(j1, k + g);
                    uint2 v = *(const uint2*)(V + (long)j * 64 + l * 4);
                    acc.x = fmaf(w, blo(v.x), acc.x);
                    acc.y = fmaf(w, bhi(v.x), acc.y);
                    acc.z = fmaf(w, blo(v.y), acc.z);
                    acc.w = fmaf(w, bhi(v.y), acc.w);
                }
            }
            if (d > 128) {
                int c2 = (d - 128) < 64 ? (d - 128) : 64;
#pragma unroll 4
                for (int k = 0; k < c2; k += 4) {
                    float w = __shfl(w2, k + g);
                    int j = __shfl(j2, k + g);
                    uint2 v = *(const uint2*)(V + (long)j * 64 + l * 4);
                    acc.x = fmaf(w, blo(v.x), acc.x);
                    acc.y = fmaf(w, bhi(v.x), acc.y);
                    acc.z = fmaf(w, blo(v.y), acc.z);
                    acc.w = fmaf(w, bhi(v.y), acc.w);
                }
            }
            for (int base = 192; base < d; base += 64) {
                int k = base + lane;
                float wr = 0.f; int jr = 0;
                if (k < d) {
                    float2 r = csr[start + k];
                    wr = __expf((r.x - m) * invT) * inv;
                    jr = __float_as_int(r.y);
                }
                int cc = (d - base) < 64 ? (d - base) : 64;
                for (int k2 = 0; k2 < cc; k2 += 4) {
                    float w = __shfl(wr, k2 + g);
                    int j = __shfl(jr, k2 + g);
                    uint2 v = *(const uint2*)(V + (long)j * 64 + l * 4);
                    acc.x = fmaf(w, blo(v.x), acc.x);
                    acc.y = fmaf(w, bhi(v.x), acc.y);
                    acc.z = fmaf(w, blo(v.y), acc.z);
                    acc.w = fmaf(w, bhi(v.y), acc.w);
                }
            }
            acc.x += __shfl_xor(acc.x, 16); acc.y += __shfl_xor(acc.y, 16);
            acc.z += __shfl_xor(acc.z, 16); acc.w += __shfl_xor(acc.w, 16);
            acc.x += __shfl_xor(acc.x, 32); acc.y += __shfl_xor(acc.y, 32);
            acc.z += __shfl_xor(acc.z, 32); acc.w += __shfl_xor(acc.w, 32);
        }
        float o = bo[lane];
#pragma unroll
        for (int kk = 0; kk < 16; ++kk) {
            float a0 = readlane_f(acc.x, kk);
            float a1 = readlane_f(acc.y, kk);
            float a2 = readlane_f(acc.z, kk);
            float a3 = readlane_f(acc.w, kk);
            o = fmaf(a0, sW[(4 * kk + 0) * 64 + lane], o);
            o = fmaf(a1, sW[(4 * kk + 1) * 64 + lane], o);
            o = fmaf(a2, sW[(4 * kk + 2) * 64 + lane], o);
            o = fmaf(a3, sW[(4 * kk + 3) * 64 + lane], o);
        }
        o = (o >= 0.f) ? o : 0.01f * o;
        msg[(long)nd * 64 + lane] = o;
    }
}

// ---------- coalesced edge weights ----------
__global__ void edge_w_kernel(const float* __restrict__ trans,
                              const int* __restrict__ seg1, const int* __restrict__ seg2,
                              const float2* __restrict__ minv1, const float2* __restrict__ minv2,
                              float* __restrict__ e1, float* __restrict__ e2,
                              int E, float invT) {
    int e = blockIdx.x * blockDim.x + threadIdx.x;
    if (e >= E) return;
    float t = trans[e];
    float2 a = minv1[seg1[e]];
    float2 b = minv2[seg2[e]];
    e1[e] = __expf((t - a.x) * invT) * a.y;
    e2[e] = __expf((t - b.x) * invT) * b.y;
}

// ---------- fallback path kernels (R2-proven, f32) ----------
__global__ void proj1_kernel(const float* __restrict__ X, int N,
                             const float* __restrict__ Wk,
                             const float* __restrict__ Wv,
                             float* __restrict__ K, float* __restrict__ V) {
    __shared__ float sWk[64 * 64];
    __shared__ float sWv[64 * 64];
    int tid = threadIdx.x;
    for (int i = tid; i < 4096; i += blockDim.x) { sWk[i] = Wk[i]; sWv[i] = Wv[i]; }
    __syncthreads();
    int wave = tid >> 6, lane = tid & 63;
    int wpb = blockDim.x >> 6;
    for (int n = blockIdx.x * wpb + wave; n < N; n += gridDim.x * wpb) {
        float x = X[n * 64 + lane];
        float ak = 0.f, av = 0.f;
#pragma unroll
        for (int k = 0; k < 64; ++k) {
            float xv = __shfl(x, k);
            ak = fmaf(xv, sWk[k * 64 + lane], ak);
            av = fmaf(xv, sWv[k * 64 + lane], av);
        }
        K[n * 64 + lane] = ak;
        V[n * 64 + lane] = av;
    }
}
__global__ void logit1_kernel(const float* __restrict__ K1, const float* __restrict__ K2,
                              const int* __restrict__ seg1, const int* __restrict__ seg2,
                              float* __restrict__ trans, int E) {
    int tid = blockIdx.x * blockDim.x + threadIdx.x;
    int e = tid >> 4, g = tid & 15;
    if (e >= E) return;
    int i1 = seg1[e], i2 = seg2[e];
    float4 a = ((const float4*)(K1 + (long)i1 * 64))[g];
    float4 b = ((const float4*)(K2 + (long)i2 * 64))[g];
    float d = a.x * b.x + a.y * b.y + a.z * b.z + a.w * b.w;
    d += __shfl_xor(d, 1);
    d += __shfl_xor(d, 2);
    d += __shfl_xor(d, 4);
    d += __shfl_xor(d, 8);
    if (g == 0) trans[e] = d;
}
__global__ void zero_deg_kernel(int* d1, int* d2, int n1, int n2) {
    int i = blockIdx.x * blockDim.x + threadIdx.x;
    if (i < n1) d1[i] = 0;
    if (i < n2) d2[i] = 0;
}
__global__ void hist_kernel(const int* __restrict__ seg1, const int* __restrict__ seg2,
                            int* deg1, int* deg2, int E) {
    int e = blockIdx.x * blockDim.x + threadIdx.x;
    if (e >= E) return;
    atomicAdd(&deg1[seg1[e]], 1);
    atomicAdd(&deg2[seg2[e]], 1);
}
__global__ void scan2_kernel(const int* __restrict__ d1, int* __restrict__ c1, int n1,
                             const int* __restrict__ d2, int* __restrict__ c2, int n2) {
    const int* deg = blockIdx.x ? d2 : d1;
    int* cur = blockIdx.x ? c2 : c1;
    int n = blockIdx.x ? n2 : n1;
    __shared__ int tmp[1024];
    __shared__ int s_carry;
    int t = threadIdx.x;
    if (t == 0) s_carry = 0;
    __syncthreads();
    for (int base = 0; base < n; base += 1024) {
        int idx = base + t;
        int v = (idx < n) ? deg[idx] : 0;
        tmp[t] = v;
        __syncthreads();
        for (int off = 1; off < 1024; off <<= 1) {
            int x = (t >= off) ? tmp[t - off] : 0;
            __syncthreads();
            tmp[t] += x;
            __syncthreads();
        }
        int excl = tmp[t] - v + s_carry;
        if (idx < n) cur[idx] = excl;
        __syncthreads();
        if (t == 0) s_carry += tmp[1023];
        __syncthreads();
    }
}
__global__ void bin_kernel(const int* __restrict__ seg1, const int* __restrict__ seg2,
                           int* cur1, int* cur2,
                           int* __restrict__ el1, int* __restrict__ el2, int E) {
    int e = blockIdx.x * blockDim.x + threadIdx.x;
    if (e >= E) return;
    int p1 = atomicAdd(&cur1[seg1[e]], 1);
    el1[p1] = e;
    int p2 = atomicAdd(&cur2[seg2[e]], 1);
    el2[p2] = e;
}
__global__ void gather_out_kernel(int N, const int* __restrict__ cur, const int* __restrict__ deg,
                                  const int* __restrict__ el, const float* __restrict__ trans,
                                  const int* __restrict__ segOther, const float* __restrict__ Vother,
                                  float* __restrict__ e_out, float* __restrict__ msg_out,
                                  const float* __restrict__ Wo, const float* __restrict__ bo,
                                  float invT) {
    __shared__ float sW[64 * 64];
    int tid = threadIdx.x;
    for (int i = tid; i < 4096; i += blockDim.x) sW[i] = Wo[i];
    __syncthreads();
    int wave = tid >> 6, lane = tid & 63;
    int wpb = blockDim.x >> 6;
    int node = blockIdx.x * wpb + wave;
    if (node >= N) return;
    int d = deg[node];
    int start = cur[node] - d;
    float acc = 0.f;
    if (d > 0) {
        float m = -INFINITY;
        for (int k = lane; k < d; k += 64) m = fmaxf(m, trans[el[start + k]]);
        m = fmaxf(m, __shfl_xor(m, 1));
        m = fmaxf(m, __shfl_xor(m, 2));
        m = fmaxf(m, __shfl_xor(m, 4));
        m = fmaxf(m, __shfl_xor(m, 8));
        m = fmaxf(m, __shfl_xor(m, 16));
        m = fmaxf(m, __shfl_xor(m, 32));
        float s = 0.f;
        for (int k = lane; k < d; k += 64) s += __expf((trans[el[start + k]] - m) * invT);
        s += __shfl_xor(s, 1);
        s += __shfl_xor(s, 2);
        s += __shfl_xor(s, 4);
        s += __shfl_xor(s, 8);
        s += __shfl_xor(s, 16);
        s += __shfl_xor(s, 32);
        float inv = 1.f / (s + 1e-8f);
        for (int base = 0; base < d; base += 64) {
            int k = base + lane;
            float w = 0.f;
            int j = 0;
            if (k < d) {
                int e = el[start + k];
                w = __expf((trans[e] - m) * invT) * inv;
                e_out[e] = w;
                j = segOther[e];
            }
            int cnt = (d - base < 64) ? (d - base) : 64;
            for (int q = 0; q < cnt; ++q) {
                float wq = __shfl(w, q);
                int jq = __shfl(j, q);
                acc = fmaf(wq, Vother[(long)jq * 64 + lane], acc);
            }
        }
    }
    float o = bo[lane];
#pragma unroll
    for (int k = 0; k < 64; ++k) {
        float xv = __shfl(acc, k);
        o = fmaf(xv, sW[k * 64 + lane], o);
    }
    o = (o >= 0.f) ? o : 0.01f * o;
    msg_out[(long)node * 64 + lane] = o;
}

extern "C" void kernel_launch(void* const* d_in, const int* in_sizes, int n_in,
                              void* d_out, int out_size, void* d_ws, size_t ws_size,
                              hipStream_t stream) {
    const float* node1 = (const float*)d_in[0];
    const int* seg1 = (const int*)d_in[1];
    const float* node2 = (const float*)d_in[3];
    const int* seg2 = (const int*)d_in[4];
    const float* Wk = (const float*)d_in[6];
    const float* Wv = (const float*)d_in[7];
    const float* Wo = (const float*)d_in[8];
    const float* bo = (const float*)d_in[9];

    int n1 = in_sizes[0] / 64;
    int n2 = in_sizes[3] / 64;
    int E = in_sizes[1];

    float* out = (float*)d_out;
    float* msg1 = out;
    float* msg2 = msg1 + (long)n1 * 64;
    float* e1 = msg2 + (long)n2 * 64;
    float* e2 = e1 + E;

    const float invT = 1.0f / sqrtf(64.0f);
    int nb1 = (n1 + BSZ - 1) >> BSH;
    int nb2 = (n2 + BSZ - 1) >> BSH;
    long Epad = (E + 1) & ~1L;

    // ---- fast-path layout (8B alignment for float2 arrays; bf16 K/V) ----
    float* ws = (float*)d_ws;
    float2* csr1 = (float2*)ws;                         // E records
    float2* csr2 = csr1 + E;                            // E
    float2* tmp1 = csr2 + E;                            // E
    float2* tmp2 = tmp1 + E;                            // E
    float* trans = (float*)(tmp2 + E);                  // Epad
    float2* minv1 = (float2*)(trans + Epad);            // n1
    float2* minv2 = minv1 + n1;                         // n2
    unsigned short* Kb1 = (unsigned short*)(minv2 + n2);// n1*64 ushort
    unsigned short* Kb2 = Kb1 + (long)n1 * 64;          // n2*64
    unsigned short* Vb1 = Kb2 + (long)n2 * 64;          // n1*64
    unsigned short* Vb2 = Vb1 + (long)n1 * 64;          // n2*64
    int* deg1 = (int*)(Vb2 + (long)n2 * 64);            // n1
    int* deg2 = deg1 + n1;                              // n2
    int* cur1 = deg2 + n2;                              // n1
    int* cur2 = cur1 + n1;                              // n2
    int* bb1 = cur2 + n2;                               // nb1+1
    int* bb2 = bb1 + nb1 + 1;                           // nb2+1
    int* bcur1 = bb2 + nb2 + 1;                         // nb1
    int* bcur2 = bcur1 + nb1;                           // nb2
    int* bcnt1 = bcur2 + nb2;                           // nb1
    int* bcnt2 = bcnt1 + nb1;                           // nb2
    long fp_words = 8L * E + Epad + 2L * (n1 + n2)      // csr/tmp + trans + minv
                  + 64L * (n1 + n2)                     // bf16 K,V both sides
                  + 2L * (n1 + n2)                      // deg, cur
                  + 3L * (nb1 + nb2) + 2;
    bool fast = (E <= (1 << 20)) && (nb1 <= MAXNB) && (nb2 <= MAXNB)
             && (n1 < (1 << 25)) && (n2 < (1 << 25))
             && ((size_t)fp_words * 4 <= ws_size);

    if (fast) {
        int total = n1 + n2;
        int gp = (total + 3) / 4;
        if (gp > 1024) gp = 1024;
        proj_kernel<<<gp, 256, 0, stream>>>(node1, n1, node2, n2, Wk, Wv,
                                            Kb1, Vb1, Kb2, Vb2,
                                            bcnt1, bcnt2, nb1, nb2);
        {
            long threads = (long)E * 16;
            int blocks = (int)((threads + 255) / 256);
            logit_kernel<<<blocks, 256, 0, stream>>>(Kb1, Kb2, seg1, seg2, trans, E);
        }
        bucket_count_kernel<<<512, 256, 0, stream>>>(seg1, seg2, E, bcnt1, bcnt2, nb1, nb2);
        bucket_scan_kernel<<<1, MAXNB, 0, stream>>>(bcnt1, bcnt2, bb1, bb2, bcur1, bcur2,
                                                    nb1, nb2, E);
        partition_kernel<<<(E + PT_TILE - 1) / PT_TILE, 256, 0, stream>>>(
            seg1, seg2, trans, E, bcur1, bcur2, tmp1, tmp2);
        bin2_kernel<<<nb1 + nb2, 256, 0, stream>>>(tmp1, bb1, n1, cur1, deg1, csr1,
                                                   tmp2, bb2, n2, cur2, deg2, csr2, nb1);
        gather_ms_kernel<<<gp, 256, 0, stream>>>(
            n1, n2, cur1, deg1, csr1, Vb2, minv1, msg1,
            cur2, deg2, csr2, Vb1, minv2, msg2, Wo, bo, invT);
        edge_w_kernel<<<(E + 255) / 256, 256, 0, stream>>>(
            trans, seg1, seg2, minv1, minv2, e1, e2, E, invT);
    } else {
        // fallback: R2-proven f32 path
        float* K1f = ws;
        float* V1f = K1f + (long)n1 * 64;
        float* K2f = V1f + (long)n1 * 64;
        float* V2f = K2f + (long)n2 * 64;
        float* transf = V2f + (long)n2 * 64;
        int* deg1f = (int*)(transf + E);
        int* deg2f = deg1f + n1;
        int* cur1f = deg2f + n2;
        int* cur2f = cur1f + n1;
        int* el1 = (int*)K1f;
        int* el2 = (int*)K2f;
        int nmax = n1 > n2 ? n1 : n2;

        proj1_kernel<<<(n1 + 3) / 4, 256, 0, stream>>>(node1, n1, Wk, Wv, K1f, V1f);
        proj1_kernel<<<(n2 + 3) / 4, 256, 0, stream>>>(node2, n2, Wk, Wv, K2f, V2f);
        {
            long threads = (long)E * 16;
            int blocks = (int)((threads + 255) / 256);
            logit1_kernel<<<blocks, 256, 0, stream>>>(K1f, K2f, seg1, seg2, transf, E);
        }
        zero_deg_kernel<<<(nmax + 255) / 256, 256, 0, stream>>>(deg1f, deg2f, n1, n2);
        hist_kernel<<<(E + 255) / 256, 256, 0, stream>>>(seg1, seg2, deg1f, deg2f, E);
        scan2_kernel<<<2, 1024, 0, stream>>>(deg1f, cur1f, n1, deg2f, cur2f, n2);
        bin_kernel<<<(E + 255) / 256, 256, 0, stream>>>(seg1, seg2, cur1f, cur2f, el1, el2, E);

        gather_out_kernel<<<(n1 + 3) / 4, 256, 0, stream>>>(
            n1, cur1f, deg1f, el1, transf, seg2, V2f, e1, msg1, Wo, bo, invT);
        gather_out_kernel<<<(n2 + 3) / 4, 256, 0, stream>>>(
            n2, cur2f, deg2f, el2, transf, seg1, V1f, e2, msg2, Wo, bo, invT);
    }
}